// Round 7
// baseline (394.894 us; speedup 1.0000x reference)
//
#include <hip/hip_runtime.h>

typedef unsigned int u32;
typedef unsigned short u16;
typedef __attribute__((ext_vector_type(8))) short short8;
typedef __attribute__((ext_vector_type(4))) float f32x4;

__device__ __forceinline__ float b2f(u16 h){ u32 x = ((u32)h) << 16; return __builtin_bit_cast(float, x); }
__device__ __forceinline__ u16 f2b(float f){
  u32 x = __builtin_bit_cast(u32, f);
  x += 0x7fffu + ((x >> 16) & 1u);
  return (u16)(x >> 16);
}
#define LOH(u) ((u16)((u) & 0xffffu))
#define HIH(u) ((u16)((u) >> 16))

__device__ __forceinline__ void gload16(const u16* g, u16* lds){
  __builtin_amdgcn_global_load_lds((const __attribute__((address_space(1))) u32*)g,
                                   (__attribute__((address_space(3))) u32*)lds, 16, 0, 0);
}

// ---------------------------------------------------------------------------
// 256x256 8-wave deep-pipelined GEMM:  C = A[M,K] * B[N,K]^T, K=1024 fixed.
// BK=64, 512 threads (2x4 waves, 128x64 per wave), double-buffered 128KB LDS,
// counted vmcnt(8), raw s_barrier, 4 phases/K-tile, setprio around MFMA.
// MODE 0: bf16 out via gp.C[z] (z==3 -> SiLU).  MODE 1: f32 out via Cf.
// ---------------------------------------------------------------------------
struct G4P { const u16* A[4]; const u16* B[4]; u16* C[4]; };

template<int MODE>
__global__ __launch_bounds__(512, 2) void gemm256_k(G4P gp, float* __restrict__ Cf)
{
  extern __shared__ u16 lds[];   // [2][ A 16384 | B 16384 ] u16
  const int tid = threadIdx.x;
  const int z = blockIdx.z;
  const u16* __restrict__ A  = gp.A[z];
  const u16* __restrict__ Bw = gp.B[z];
  const int wid = tid >> 6, lane = tid & 63;
  const int wr = wid >> 2, wc = wid & 3;
  const int l16 = lane & 15, kq = lane >> 4;
  const long row0 = (long)blockIdx.x * 256;
  const long col0 = (long)blockIdx.y * 256;

  f32x4 acc[8][4];
#pragma unroll
  for (int i = 0; i < 8; i++)
#pragma unroll
    for (int j = 0; j < 4; j++) acc[i][j] = (f32x4)0.0f;

  // staging: chunk c = tid + it*512; row=c>>3, k8=(c&7)*8; lds off = c*8
  const int srow = tid >> 3, sk8 = (tid & 7) * 8;
  const u16* Agp = A  + (row0 + srow) * 1024 + sk8;
  const u16* Bgp = Bw + (col0 + srow) * 1024 + sk8;

  auto STAGE = [&](int buf, int kt){
    u16* Ab = lds + buf * 32768;
    u16* Bb = Ab + 16384;
    const int ko = kt * 64;
#pragma unroll
    for (int it = 0; it < 4; it++){
      gload16(Agp + (long)it * 65536 + ko, Ab + (tid + it * 512) * 8);
      gload16(Bgp + (long)it * 65536 + ko, Bb + (tid + it * 512) * 8);
    }
  };

  STAGE(0, 0);
  const int NT = 16;   // K=1024 / BK=64
  for (int t = 0; t < NT; t++){
    const int cur = t & 1;
    if (t + 1 < NT){
      STAGE(cur ^ 1, t + 1);
      asm volatile("s_waitcnt vmcnt(8)" ::: "memory");   // tile t landed; t+1 in flight
    } else {
      asm volatile("s_waitcnt vmcnt(0)" ::: "memory");
    }
    __builtin_amdgcn_sched_barrier(0);
    __builtin_amdgcn_s_barrier();
    const u16* Ab = lds + cur * 32768;
    const u16* Bb = Ab + 16384;

    short8 afr[4][2], bfr0[2][2], bfr1[2][2];
    // ---- phase 0: quadrant (miH=0, niH=0) ----
#pragma unroll
    for (int mi = 0; mi < 4; mi++)
#pragma unroll
      for (int ks = 0; ks < 2; ks++)
        afr[mi][ks] = *(const short8*)&Ab[(wr*128 + mi*16 + l16)*64 + ks*32 + kq*8];
#pragma unroll
    for (int ni = 0; ni < 2; ni++)
#pragma unroll
      for (int ks = 0; ks < 2; ks++)
        bfr0[ni][ks] = *(const short8*)&Bb[(wc*64 + ni*16 + l16)*64 + ks*32 + kq*8];
    asm volatile("s_waitcnt lgkmcnt(0)" ::: "memory");
    __builtin_amdgcn_sched_barrier(0);
    __builtin_amdgcn_s_setprio(1);
#pragma unroll
    for (int mi = 0; mi < 4; mi++)
#pragma unroll
      for (int ni = 0; ni < 2; ni++)
#pragma unroll
        for (int ks = 0; ks < 2; ks++)
          acc[mi][ni] = __builtin_amdgcn_mfma_f32_16x16x32_bf16(afr[mi][ks], bfr0[ni][ks], acc[mi][ni], 0, 0, 0);
    __builtin_amdgcn_s_setprio(0);
    __builtin_amdgcn_s_barrier();
    // ---- phase 1: (0,1) ----
#pragma unroll
    for (int ni = 0; ni < 2; ni++)
#pragma unroll
      for (int ks = 0; ks < 2; ks++)
        bfr1[ni][ks] = *(const short8*)&Bb[(wc*64 + (2+ni)*16 + l16)*64 + ks*32 + kq*8];
    asm volatile("s_waitcnt lgkmcnt(0)" ::: "memory");
    __builtin_amdgcn_sched_barrier(0);
    __builtin_amdgcn_s_setprio(1);
#pragma unroll
    for (int mi = 0; mi < 4; mi++)
#pragma unroll
      for (int ni = 0; ni < 2; ni++)
#pragma unroll
        for (int ks = 0; ks < 2; ks++)
          acc[mi][2+ni] = __builtin_amdgcn_mfma_f32_16x16x32_bf16(afr[mi][ks], bfr1[ni][ks], acc[mi][2+ni], 0, 0, 0);
    __builtin_amdgcn_s_setprio(0);
    __builtin_amdgcn_s_barrier();
    // ---- phase 2: (1,0) ----
#pragma unroll
    for (int mi = 0; mi < 4; mi++)
#pragma unroll
      for (int ks = 0; ks < 2; ks++)
        afr[mi][ks] = *(const short8*)&Ab[(wr*128 + (4+mi)*16 + l16)*64 + ks*32 + kq*8];
    asm volatile("s_waitcnt lgkmcnt(0)" ::: "memory");
    __builtin_amdgcn_sched_barrier(0);
    __builtin_amdgcn_s_setprio(1);
#pragma unroll
    for (int mi = 0; mi < 4; mi++)
#pragma unroll
      for (int ni = 0; ni < 2; ni++)
#pragma unroll
        for (int ks = 0; ks < 2; ks++)
          acc[4+mi][ni] = __builtin_amdgcn_mfma_f32_16x16x32_bf16(afr[mi][ks], bfr0[ni][ks], acc[4+mi][ni], 0, 0, 0);
    __builtin_amdgcn_s_setprio(0);
    __builtin_amdgcn_s_barrier();
    // ---- phase 3: (1,1) — no LDS reads ----
    __builtin_amdgcn_s_setprio(1);
#pragma unroll
    for (int mi = 0; mi < 4; mi++)
#pragma unroll
      for (int ni = 0; ni < 2; ni++)
#pragma unroll
        for (int ks = 0; ks < 2; ks++)
          acc[4+mi][2+ni] = __builtin_amdgcn_mfma_f32_16x16x32_bf16(afr[mi][ks], bfr1[ni][ks], acc[4+mi][2+ni], 0, 0, 0);
    __builtin_amdgcn_s_setprio(0);
    __builtin_amdgcn_s_barrier();   // protects buf cur^? before next iter's STAGE overwrites
  }

  const bool SILU = (MODE == 0) && (z == 3);
#pragma unroll
  for (int mi = 0; mi < 8; mi++){
#pragma unroll
    for (int qq = 0; qq < 4; qq++){
      const long r = row0 + wr*128 + mi*16 + kq*4 + qq;
      if (MODE == 0){
        u16* crow = gp.C[z] + r * 1024 + col0 + wc*64 + l16;
#pragma unroll
        for (int ni = 0; ni < 4; ni++){
          float v = acc[mi][ni][qq];
          if (SILU) v = v / (1.0f + expf(-v));
          crow[ni * 16] = f2b(v);
        }
      } else {
        float* crow = Cf + r * 1024 + col0 + wc*64 + l16;
#pragma unroll
        for (int ni = 0; ni < 4; ni++)
          crow[ni * 16] = acc[mi][ni][qq];
      }
    }
  }
}

// ---------------------------------------------------------------------------
// Generic MFMA GEMM: C[M,N] = A[M,K] * B[N,K]^T   (A,B bf16 K-contiguous)
// 128x128 tile, BK=32, 256 threads (4 waves 2x2), 16x16x32 bf16 MFMA.
// EPI: 0 bf16, 1 tanh bf16, 3 decay f32 (e_vec), 4 silu bf16, 5 plain f32
// ---------------------------------------------------------------------------
template<int EPI>
__global__ __launch_bounds__(256) void gemm_bt(
    const u16* __restrict__ A, int lda,
    const u16* __restrict__ B, int ldb,
    void* __restrict__ Cv, int ldc, int K,
    const float* __restrict__ e_vec)
{
  __shared__ u16 As[4096];
  __shared__ u16 Bs[4096];
  const int tid = threadIdx.x;
  const int wave = tid >> 6, lane = tid & 63;
  const int wr = wave >> 1, wc = wave & 1;
  const int l16 = lane & 15, kq = lane >> 4;
  const long row0 = (long)blockIdx.x * 128;
  const long col0 = (long)blockIdx.y * 128;

  f32x4 acc[4][4];
#pragma unroll
  for (int i = 0; i < 4; i++)
#pragma unroll
    for (int j = 0; j < 4; j++) acc[i][j] = (f32x4)0.0f;

  const int c0 = tid, c1 = tid + 256;
  const u16* Ag0 = A + (row0 + (c0 >> 2)) * (long)lda + (c0 & 3) * 8;
  const u16* Ag1 = A + (row0 + (c1 >> 2)) * (long)lda + (c1 & 3) * 8;
  const u16* Bg0 = B + (col0 + (c0 >> 2)) * (long)ldb + (c0 & 3) * 8;
  const u16* Bg1 = B + (col0 + (c1 >> 2)) * (long)ldb + (c1 & 3) * 8;
  u16* Al0 = &As[c0 * 8]; u16* Al1 = &As[c1 * 8];
  u16* Bl0 = &Bs[c0 * 8]; u16* Bl1 = &Bs[c1 * 8];

  for (int kk = 0; kk < K; kk += 32){
    __syncthreads();
    gload16(Ag0 + kk, Al0);
    gload16(Ag1 + kk, Al1);
    gload16(Bg0 + kk, Bl0);
    gload16(Bg1 + kk, Bl1);
    __syncthreads();
    short8 af[4], bfr[4];
#pragma unroll
    for (int mi = 0; mi < 4; mi++) af[mi]  = *(const short8*)&As[(wr*64 + mi*16 + l16)*32 + kq*8];
#pragma unroll
    for (int ni = 0; ni < 4; ni++) bfr[ni] = *(const short8*)&Bs[(wc*64 + ni*16 + l16)*32 + kq*8];
#pragma unroll
    for (int mi = 0; mi < 4; mi++)
#pragma unroll
      for (int ni = 0; ni < 4; ni++)
        acc[mi][ni] = __builtin_amdgcn_mfma_f32_16x16x32_bf16(af[mi], bfr[ni], acc[mi][ni], 0, 0, 0);
  }

#pragma unroll
  for (int mi = 0; mi < 4; mi++){
#pragma unroll
    for (int qq = 0; qq < 4; qq++){
      const long r = row0 + wr*64 + mi*16 + kq*4 + qq;   // C/D: row=(lane>>4)*4+reg
#pragma unroll
      for (int ni = 0; ni < 4; ni++){
        const long c = col0 + wc*64 + ni*16 + l16;        //      col=lane&15
        const float v = acc[mi][ni][qq];
        if (EPI == 0){
          ((u16*)Cv)[r * ldc + c] = f2b(v);
        } else if (EPI == 1){
          ((u16*)Cv)[r * ldc + c] = f2b(tanhf(v));
        } else if (EPI == 3){
          const float w = v + e_vec[c];
          ((float*)Cv)[r * ldc + c] = expf(-expf(w));
        } else if (EPI == 4){
          ((u16*)Cv)[r * ldc + c] = f2b(v / (1.0f + expf(-v)));
        } else {
          ((float*)Cv)[r * ldc + c] = v;
        }
      }
    }
  }
}

// ---------------------------------------------------------------------------
// Fused 5-way token-mix GEMM, z-loop INSIDE: one block computes the 128x128
// tile for all 5 f's.  C_f = bf16( x + xx * (tm_f + MIXB_f @ W2T_f^T) ).
// A-tile [128][160] staged once (2560 16B chunks); ex/exx hoisted to regs.
// ---------------------------------------------------------------------------
struct Mix5P { const u16* ex; const u16* exx; u16* out[5]; const float* tm[5]; };

__global__ __launch_bounds__(256) void gemm_mix5(
    const u16* __restrict__ Am, const u16* __restrict__ W2T, Mix5P mp)
{
  __shared__ u16 As[128 * 160];   // 40 KB, stride 160
  __shared__ u16 Bs[128 * 32];    // 8 KB
  const int tid = threadIdx.x;
  const int wave = tid >> 6, lane = tid & 63;
  const int wr = wave >> 1, wc = wave & 1;
  const int l16 = lane & 15, kq = lane >> 4;
  const long row0 = (long)blockIdx.x * 128;
  const long col0 = (long)blockIdx.y * 128;

  // stage A-tile [128][160]: 160 u16/row = 20 chunks/row, 2560 chunks total.
#pragma unroll
  for (int it = 0; it < 10; it++){
    const int c = tid + it * 256;
    const int r = c / 20, c8 = c - r * 20;
    gload16(Am + (row0 + r) * 256 + c8 * 8, &As[c * 8]);
  }

  // hoisted ex/exx loads: 64 positions, packed (ex lo | exx hi)
  u32 pxx[64];
#pragma unroll
  for (int mi = 0; mi < 4; mi++)
#pragma unroll
    for (int qq = 0; qq < 4; qq++){
      const long r = row0 + wr*64 + mi*16 + kq*4 + qq;
#pragma unroll
      for (int ni = 0; ni < 4; ni++){
        const long c = col0 + wc*64 + ni*16 + l16;
        const u16 a = mp.ex[r * 1024 + c];
        const u16 b = mp.exx[r * 1024 + c];
        pxx[mi*16 + qq*4 + ni] = (u32)a | ((u32)b << 16);
      }
    }

  for (int z = 0; z < 5; z++){
    __syncthreads();
    const u16* B = W2T + z * 32768;
#pragma unroll
    for (int it = 0; it < 2; it++){
      const int c = tid + it * 256;
      gload16(B + (col0 + (c >> 2)) * 32 + (c & 3) * 8, &Bs[c * 8]);
    }
    __syncthreads();
    short8 af[4], bfr[4];
#pragma unroll
    for (int mi = 0; mi < 4; mi++) af[mi]  = *(const short8*)&As[(wr*64 + mi*16 + l16)*160 + z*32 + kq*8];
#pragma unroll
    for (int ni = 0; ni < 4; ni++) bfr[ni] = *(const short8*)&Bs[(wc*64 + ni*16 + l16)*32 + kq*8];
    f32x4 acc[4][4];
#pragma unroll
    for (int i = 0; i < 4; i++)
#pragma unroll
      for (int j = 0; j < 4; j++) acc[i][j] = (f32x4)0.0f;
#pragma unroll
    for (int mi = 0; mi < 4; mi++)
#pragma unroll
      for (int ni = 0; ni < 4; ni++)
        acc[mi][ni] = __builtin_amdgcn_mfma_f32_16x16x32_bf16(af[mi], bfr[ni], acc[mi][ni], 0, 0, 0);

    const float* tm = mp.tm[z];
    float tmv[4];
#pragma unroll
    for (int ni = 0; ni < 4; ni++) tmv[ni] = tm[col0 + wc*64 + ni*16 + l16];
    u16* C = mp.out[z];
#pragma unroll
    for (int mi = 0; mi < 4; mi++){
#pragma unroll
      for (int qq = 0; qq < 4; qq++){
        const long r = row0 + wr*64 + mi*16 + kq*4 + qq;
        u16* crow = C + r * 1024 + col0 + wc*64 + l16;
#pragma unroll
        for (int ni = 0; ni < 4; ni++){
          const u32 pk = pxx[mi*16 + qq*4 + ni];
          const float xc = b2f(LOH(pk));
          const float xx = b2f(HIH(pk));
          crow[ni * 16] = f2b(xc + xx * (tmv[ni] + acc[mi][ni][qq]));
        }
      }
    }
  }
}

// ---------------------------------------------------------------------------
// XM = bf16(x + (xp-x)*tmx);  XBF = bf16(x);  XX = bf16(xp - x)
// ---------------------------------------------------------------------------
__global__ __launch_bounds__(256) void mkxm_k(const float* __restrict__ X,
    const float* __restrict__ tmx, u16* __restrict__ XM,
    u16* __restrict__ XBF, u16* __restrict__ XXo)
{
  const long idx = (long)blockIdx.x * 256 + threadIdx.x;
  const long m = idx >> 8;
  const int c4 = (int)(idx & 255) * 4;
  const float4 x = *(const float4*)(X + m * 1024 + c4);
  float4 p = make_float4(0.f, 0.f, 0.f, 0.f);
  if ((m & 2047) != 0) p = *(const float4*)(X + (m - 1) * 1024 + c4);
  const float4 t = *(const float4*)(tmx + c4);
  ushort4 o;
  o.x = f2b(x.x + (p.x - x.x) * t.x);
  o.y = f2b(x.y + (p.y - x.y) * t.y);
  o.z = f2b(x.z + (p.z - x.z) * t.z);
  o.w = f2b(x.w + (p.w - x.w) * t.w);
  *(ushort4*)(XM + m * 1024 + c4) = o;
  ushort4 ob; ob.x = f2b(x.x); ob.y = f2b(x.y); ob.z = f2b(x.z); ob.w = f2b(x.w);
  *(ushort4*)(XBF + m * 1024 + c4) = ob;
  ushort4 ox; ox.x = f2b(p.x - x.x); ox.y = f2b(p.y - x.y); ox.z = f2b(p.z - x.z); ox.w = f2b(p.w - x.w);
  *(ushort4*)(XXo + m * 1024 + c4) = ox;
}

// ---------------------------------------------------------------------------
// 5 weight casts in one launch (blockIdx.y = which)
// ---------------------------------------------------------------------------
struct Cast5P { const float* s[5]; u16* d[5]; };
__global__ __launch_bounds__(256) void cast5_k(Cast5P cp)
{
  const int w = blockIdx.y;
  const long i = (long)blockIdx.x * 256 + threadIdx.x;
  const float4 v = ((const float4*)cp.s[w])[i];
  ushort4 o; o.x = f2b(v.x); o.y = f2b(v.y); o.z = f2b(v.z); o.w = f2b(v.w);
  ((ushort4*)cp.d[w])[i] = o;
}

// ---------------------------------------------------------------------------
// dst[n][k] = bf16( (n < Ccols) ? src[k][n] : 0 )   dst [dstR][R], idx = n*R+k
// ---------------------------------------------------------------------------
__global__ __launch_bounds__(256) void tpad_k(const float* __restrict__ src,
    u16* __restrict__ dst, int R, int Ccols, long total)
{
  const long idx = (long)blockIdx.x * 256 + threadIdx.x;
  if (idx >= total) return;
  const int k = (int)(idx % R);
  const int n = (int)(idx / R);
  dst[idx] = (n < Ccols) ? f2b(src[(long)k * Ccols + n]) : (u16)0;
}

// ---------------------------------------------------------------------------
// MW2 [5][32][1024] -> W2T [5][1024][32] bf16, one launch
// ---------------------------------------------------------------------------
__global__ __launch_bounds__(256) void tpw2_k(const float* __restrict__ src,
    u16* __restrict__ dst)
{
  const int n = blockIdx.x * 256 + threadIdx.x;    // < 163840
  const int k = n & 31;
  const int col = (n >> 5) & 1023;
  const int f = n >> 15;
  dst[n] = f2b(src[f * 32768 + k * 1024 + col]);
}

// ---------------------------------------------------------------------------
// WKV6 stage 1 (MFMA). Block per (b,h,chunk).
//  M = r̃·k̃ᵀ (masked s<i), Y = M·V + diag·v (bf16 out), A = k̃ᵀ·V, r̃ -> Rg, Pg.
// ---------------------------------------------------------------------------
__global__ __launch_bounds__(256) void wkv_s1(
    u16* __restrict__ Rg, const u16* __restrict__ Kg, const u16* __restrict__ Vg,
    const float* __restrict__ Dg, const float* __restrict__ Ug,
    u16* __restrict__ Yg, float* __restrict__ Ag, float* __restrict__ Pg)
{
  __shared__ u16 RT_[64 * 72];     // r -> r̃  [i][k]
  __shared__ u16 KT_[64 * 72];     // k -> k̃  [s][k]
  __shared__ u16 KTT_[64 * 72];    // k̃ᵀ [k][s]
  __shared__ u16 V_[64 * 72];      // V [s][j]
  __shared__ u16 VT_[64 * 72];     // Vᵀ [j][s]
  __shared__ char UD_[64 * 68 * 4];// D f32 [i][68], then M u16 [i][72]
  __shared__ float us_[64];
  __shared__ float dg4_[256];
  __shared__ float dg_[64];
  float* D_ = (float*)UD_;
  u16*  M_  = (u16*)UD_;

  const int tid = threadIdx.x;
  const int bh = blockIdx.x >> 5, ch = blockIdx.x & 31;
  const int b = bh >> 4, h = bh & 15, cb = h * 64;
  const long rowb = (long)b * 2048 + ch * 64;

  if (tid < 64) us_[tid] = Ug[cb + tid];

  const int iS = tid >> 2, sg = tid & 3;
  // ---- P0: stage r,k,v(,vT),d
  {
    const long go = (rowb + iS) * 1024 + cb + sg * 16;
    uint4 a0 = *(const uint4*)(Rg + go);
    uint4 a1 = *(const uint4*)(Rg + go + 8);
    u32* rd = (u32*)&RT_[iS * 72 + sg * 16];
    rd[0]=a0.x; rd[1]=a0.y; rd[2]=a0.z; rd[3]=a0.w;
    rd[4]=a1.x; rd[5]=a1.y; rd[6]=a1.z; rd[7]=a1.w;
    a0 = *(const uint4*)(Kg + go); a1 = *(const uint4*)(Kg + go + 8);
    u32* kd = (u32*)&KT_[iS * 72 + sg * 16];
    kd[0]=a0.x; kd[1]=a0.y; kd[2]=a0.z; kd[3]=a0.w;
    kd[4]=a1.x; kd[5]=a1.y; kd[6]=a1.z; kd[7]=a1.w;
    a0 = *(const uint4*)(Vg + go); a1 = *(const uint4*)(Vg + go + 8);
    u32* vd = (u32*)&V_[iS * 72 + sg * 16];
    vd[0]=a0.x; vd[1]=a0.y; vd[2]=a0.z; vd[3]=a0.w;
    vd[4]=a1.x; vd[5]=a1.y; vd[6]=a1.z; vd[7]=a1.w;
    const u32 vw[8] = {a0.x,a0.y,a0.z,a0.w,a1.x,a1.y,a1.z,a1.w};
#pragma unroll
    for (int e = 0; e < 8; e++){
      VT_[(sg*16 + 2*e    ) * 72 + iS] = LOH(vw[e]);
      VT_[(sg*16 + 2*e + 1) * 72 + iS] = HIH(vw[e]);
    }
    const float4* dsrc = (const float4*)(Dg + go);
    float4* dd = (float4*)&D_[iS * 68 + sg * 16];
    dd[0]=dsrc[0]; dd[1]=dsrc[1]; dd[2]=dsrc[2]; dd[3]=dsrc[3];
  }
  __syncthreads();
  // ---- P0b: diag partials with RAW r,k
  {
    const int i = tid & 63, q = tid >> 6;
    const u32* rr = (const u32*)&RT_[i * 72 + q * 16];
    const u32* kr = (const u32*)&KT_[i * 72 + q * 16];
    const float* up = &us_[q * 16];
    float ds = 0.0f;
#pragma unroll
    for (int e = 0; e < 8; e++){
      ds += b2f(LOH(rr[e])) * up[2*e]   * b2f(LOH(kr[e]));
      ds += b2f(HIH(rr[e])) * up[2*e+1] * b2f(HIH(kr[e]));
    }
    dg4_[i * 4 + q] = ds;
  }
  __syncthreads();
  // ---- P0c: prefix decay; RT->r̃, KT->k̃ (and KTT); diag finalize; Pg
  if (tid < 64){
    const int k = tid;
    dg_[k] = dg4_[k*4] + dg4_[k*4+1] + dg4_[k*4+2] + dg4_[k*4+3];
    float pz = 1.0f;
#pragma unroll 4
    for (int i = 0; i < 64; i++){
      const float d = D_[i * 68 + k];
      const int ro = i * 72 + k;
      RT_[ro] = f2b(b2f(RT_[ro]) * pz);
      pz *= d;
      const u16 kb = f2b(b2f(KT_[ro]) * (1.0f / pz));
      KT_[ro] = kb;
      KTT_[k * 72 + i] = kb;
    }
    Pg[((long)bh * 32 + ch) * 64 + k] = pz;
  }
  __syncthreads();
  // ---- writeback r̃ to Rg
  {
    const u32* rr = (const u32*)&RT_[iS * 72 + sg * 16];
    u32* out = (u32*)(Rg + (rowb + iS) * 1024 + cb + sg * 16);
#pragma unroll
    for (int e = 0; e < 8; e++) out[e] = rr[e];
  }
  const int wave = tid >> 6, lane = tid & 63;
  const int wr = wave >> 1, wc = wave & 1;
  const int l16 = lane & 15, kq = lane >> 4;
  // ---- P2: M = r̃·k̃ᵀ, mask s<i, store bf16 to M_
  {
    f32x4 acc[2][2];
#pragma unroll
    for (int a = 0; a < 2; a++)
#pragma unroll
      for (int c = 0; c < 2; c++) acc[a][c] = (f32x4)0.0f;
#pragma unroll
    for (int ks = 0; ks < 2; ks++){
      short8 af[2], bf[2];
#pragma unroll
      for (int mi = 0; mi < 2; mi++) af[mi] = *(const short8*)&RT_[(wr*32 + mi*16 + l16)*72 + ks*32 + kq*8];
#pragma unroll
      for (int ni = 0; ni < 2; ni++) bf[ni] = *(const short8*)&KT_[(wc*32 + ni*16 + l16)*72 + ks*32 + kq*8];
#pragma unroll
      for (int mi = 0; mi < 2; mi++)
#pragma unroll
        for (int ni = 0; ni < 2; ni++)
          acc[mi][ni] = __builtin_amdgcn_mfma_f32_16x16x32_bf16(af[mi], bf[ni], acc[mi][ni], 0, 0, 0);
    }
    __syncthreads();    // D_ dead; M_ union becomes valid
#pragma unroll
    for (int mi = 0; mi < 2; mi++)
#pragma unroll
      for (int ni = 0; ni < 2; ni++)
#pragma unroll
        for (int qq = 0; qq < 4; qq++){
          const int ii = wr*32 + mi*16 + kq*4 + qq;
          const int ss = wc*32 + ni*16 + l16;
          M_[ii * 72 + ss] = f2b(ss < ii ? acc[mi][ni][qq] : 0.0f);
        }
  }
  __syncthreads();
  // ---- P3+P4: Y = M·V + diag·v ; A = k̃ᵀ·V
  {
    f32x4 accY[2][2], accA[2][2];
#pragma unroll
    for (int a = 0; a < 2; a++)
#pragma unroll
      for (int c = 0; c < 2; c++){ accY[a][c] = (f32x4)0.0f; accA[a][c] = (f32x4)0.0f; }
#pragma unroll
    for (int ks = 0; ks < 2; ks++){
      short8 am[2], ak[2], bv[2];
#pragma unroll
      for (int mi = 0; mi < 2; mi++){
        am[mi] = *(const short8*)&M_[(wr*32 + mi*16 + l16)*72 + ks*32 + kq*8];
        ak[mi] = *(const short8*)&KTT_[(wr*32 + mi*16 + l16)*72 + ks*32 + kq*8];
      }
#pragma unroll
      for (int ni = 0; ni < 2; ni++) bv[ni] = *(const short8*)&VT_[(wc*32 + ni*16 + l16)*72 + ks*32 + kq*8];
#pragma unroll
      for (int mi = 0; mi < 2; mi++)
#pragma unroll
        for (int ni = 0; ni < 2; ni++){
          accY[mi][ni] = __builtin_amdgcn_mfma_f32_16x16x32_bf16(am[mi], bv[ni], accY[mi][ni], 0, 0, 0);
          accA[mi][ni] = __builtin_amdgcn_mfma_f32_16x16x32_bf16(ak[mi], bv[ni], accA[mi][ni], 0, 0, 0);
        }
    }
    float* abase = Ag + ((long)bh * 32 + ch) * 4096;
#pragma unroll
    for (int mi = 0; mi < 2; mi++)
#pragma unroll
      for (int qq = 0; qq < 4; qq++){
        const int ii = wr*32 + mi*16 + kq*4 + qq;
        u16* yrow = Yg + (rowb + ii) * 1024 + cb;
        float* arow = abase + ii * 64;
#pragma unroll
        for (int ni = 0; ni < 2; ni++){
          const int jj = wc*32 + ni*16 + l16;
          const float yv = accY[mi][ni][qq] + dg_[ii] * b2f(V_[ii * 72 + jj]);
          yrow[jj] = f2b(yv);
          arow[jj] = accA[mi][ni][qq];
        }
      }
  }
}

// ---------------------------------------------------------------------------
// WKV6 stage 2 — inter-chunk recurrence S_{c+1} = ps_c*(S_c + A_c).
// ---------------------------------------------------------------------------
__global__ __launch_bounds__(256) void wkv_s2(
    const float* __restrict__ Ag, const float* __restrict__ Pg, float* __restrict__ Sg)
{
  const int tid = threadIdx.x;
  const int bh = blockIdx.x >> 2, kq = blockIdx.x & 3;
  const int kk = tid >> 4, jo = tid & 15;
  const int krow = kq * 16 + kk;
  const long base = (long)bh * 32;
  float4 S = make_float4(0.f, 0.f, 0.f, 0.f);
  for (int c = 0; c < 32; c++){
    const long mo = (base + c) * 4096 + krow * 64 + jo * 4;
    *(float4*)(Sg + mo) = S;
    const float4 a = *(const float4*)(Ag + mo);
    const float ps = Pg[(base + c) * 64 + krow];
    S.x = ps * (S.x + a.x); S.y = ps * (S.y + a.y);
    S.z = ps * (S.z + a.z); S.w = ps * (S.w + a.w);
  }
}

// ---------------------------------------------------------------------------
// WKV6 stage 3 — cross term: Yg += rt~ . S_chunkstart (bf16 RMW).
// ---------------------------------------------------------------------------
__global__ __launch_bounds__(256) void wkv_s3(
    const u16* __restrict__ Rtg, const float* __restrict__ Sg, u16* __restrict__ Yg)
{
  __shared__ float Ss[4096];        // [k][j]
  __shared__ u16 RTs[64 * 66];
  const int tid = threadIdx.x;
  const int bh = blockIdx.x >> 5, ch = blockIdx.x & 31;
  if (ch == 0) return;
  const int b = bh >> 4, h = bh & 15, cb = h * 64;
  const long rowb = (long)b * 2048 + ch * 64;

  {
    const float4* sp = (const float4*)(Sg + ((long)bh * 32 + ch) * 4096);
    float4* sd = (float4*)Ss;
#pragma unroll
    for (int e = 0; e < 4; e++) sd[tid + e * 256] = sp[tid + e * 256];
  }
  {
    const int iS = tid >> 2, sg4 = tid & 3;
    const u32* src = (const u32*)(Rtg + (rowb + iS) * 1024 + cb + sg4 * 16);
    u32* dst = (u32*)&RTs[iS * 66 + sg4 * 16];
#pragma unroll
    for (int e = 0; e < 8; e++) dst[e] = src[e];
  }
  __syncthreads();

  const int i_ = tid & 63, q = tid >> 6, jb = q * 16;
  float rt[64];
  {
    const u32* rr = (const u32*)&RTs[i_ * 66];
#pragma unroll
    for (int kk = 0; kk < 32; kk++){
      const u32 u = rr[kk];
      rt[2*kk] = b2f(LOH(u)); rt[2*kk+1] = b2f(HIH(u));
    }
  }
  u16* yo = Yg + (rowb + i_) * 1024 + cb + jb;
  float y[16];
  {
    const u32* yp = (const u32*)yo;
#pragma unroll
    for (int j2 = 0; j2 < 8; j2++){
      const u32 u = yp[j2];
      y[2*j2] = b2f(LOH(u)); y[2*j2+1] = b2f(HIH(u));
    }
  }
#pragma unroll
  for (int k = 0; k < 64; k++){
    const float rk = rt[k];
    const float4* sr = (const float4*)&Ss[k * 64 + jb];
#pragma unroll
    for (int j4 = 0; j4 < 4; j4++){
      const float4 sv = sr[j4];
      y[4*j4+0] += rk*sv.x; y[4*j4+1] += rk*sv.y; y[4*j4+2] += rk*sv.z; y[4*j4+3] += rk*sv.w;
    }
  }
  {
    u32* yp = (u32*)yo;
#pragma unroll
    for (int j2 = 0; j2 < 8; j2++)
      yp[j2] = (u32)f2b(y[2*j2]) | ((u32)f2b(y[2*j2+1]) << 16);
  }
}

// ---------------------------------------------------------------------------
// GroupNorm over each head's 64 channels, then * g   (one block per bt row)
// ---------------------------------------------------------------------------
__global__ __launch_bounds__(256) void gnorm_k(const u16* __restrict__ Y,
    const u16* __restrict__ G, const float* __restrict__ lng,
    const float* __restrict__ lnb, u16* __restrict__ Z)
{
  const long row = blockIdx.x;
  const int tid = threadIdx.x;
  const int hh = tid >> 4, l = tid & 15;
  const int c = hh * 64 + l * 4;
  const u32* yp = (const u32*)(Y + row * 1024 + c);
  const u32 y01 = yp[0], y23 = yp[1];
  const float vv[4] = {b2f(LOH(y01)), b2f(HIH(y01)), b2f(LOH(y23)), b2f(HIH(y23))};
  float s = vv[0] + vv[1] + vv[2] + vv[3];
  float sq = vv[0]*vv[0] + vv[1]*vv[1] + vv[2]*vv[2] + vv[3]*vv[3];
#pragma unroll
  for (int off = 1; off < 16; off <<= 1){ s += __shfl_xor(s, off); sq += __shfl_xor(sq, off); }
  const float mean = s * 0.015625f;
  const float var = sq * 0.015625f - mean * mean;
  const float rstd = rsqrtf(var + 6.4e-4f);   // eps = 1e-5 * 64
  const uint2 gg = *(const uint2*)(G + row * 1024 + c);
  const float4 lg = *(const float4*)(lng + c);
  const float4 lb = *(const float4*)(lnb + c);
  const float lgs[4] = {lg.x, lg.y, lg.z, lg.w};
  const float lbs[4] = {lb.x, lb.y, lb.z, lb.w};
  const u32 gs[2] = {gg.x, gg.y};
  ushort4 o;
  u16* op = (u16*)&o;
#pragma unroll
  for (int e = 0; e < 4; e++){
    const float gv = b2f((e & 1) ? HIH(gs[e >> 1]) : LOH(gs[e >> 1]));
    op[e] = f2b(((vv[e] - mean) * rstd * lgs[e] + lbs[e]) * gv);
  }
  *(ushort4*)(Z + row * 1024 + c) = o;
}

// ---------------------------------------------------------------------------
extern "C" void kernel_launch(void* const* d_in, const int* in_sizes, int n_in,
                              void* d_out, int out_size, void* d_ws, size_t ws_size,
                              hipStream_t stream)
{
  (void)in_sizes; (void)n_in; (void)out_size; (void)ws_size;
  const float* X    = (const float*)d_in[0];
  const float* TMX  = (const float*)d_in[1];
  const float* TMW  = (const float*)d_in[2];
  const float* TMK  = (const float*)d_in[3];
  const float* TMV  = (const float*)d_in[4];
  const float* TMR  = (const float*)d_in[5];
  const float* TMG  = (const float*)d_in[6];
  const float* MW1  = (const float*)d_in[7];
  const float* MW2  = (const float*)d_in[8];
  const float* TD   = (const float*)d_in[9];
  const float* TDW1 = (const float*)d_in[10];
  const float* TDW2 = (const float*)d_in[11];
  const float* U    = (const float*)d_in[12];
  const float* WR   = (const float*)d_in[13];
  const float* WK   = (const float*)d_in[14];
  const float* WV   = (const float*)d_in[15];
  const float* WG   = (const float*)d_in[16];
  const float* WO   = (const float*)d_in[17];
  const float* LNG  = (const float*)d_in[18];
  const float* LNB  = (const float*)d_in[19];

  char* ws = (char*)d_ws;
  const size_t SLOT = 16777216ULL;     // B*T*C bf16 bytes
  u16* S1 = (u16*)(ws + 0 * SLOT);     // XM  -> Rb (-> rt~)
  u16* S2 = (u16*)(ws + 1 * SLOT);     // XW  -> Y (bf16)
  u16* S3 = (u16*)(ws + 2 * SLOT);     // XK
  u16* S4 = (u16*)(ws + 3 * SLOT);     // XV  -> Z
  u16* S5 = (u16*)(ws + 4 * SLOT);     // XR  -> DEC lo
  u16* S6 = (u16*)(ws + 5 * SLOT);     // XG  -> DEC hi
  u16* S7 = (u16*)(ws + 6 * SLOT);     // XBF -> Kb -> Sg lo
  u16* S8 = (u16*)(ws + 7 * SLOT);     // XX  -> Vb -> Sg hi
  u16* S9 = (u16*)(ws + 8 * SLOT);     // Gb
  char* p = ws + 9 * SLOT;
  auto alloc = [&](size_t bytes) -> void* {
    void* q = p; p += (bytes + 255) & ~(size_t)255; return q;
  };
  u16* MIXB = (u16*)alloc(8192ULL * 256 * 2);
  u16* Hb   = (u16*)alloc(8192ULL * 128 * 2);
  u16* W1T  = (u16*)alloc(256ULL * 1024 * 2);
  u16* W2T  = (u16*)alloc(5ULL * 1024 * 32 * 2);
  u16* TW1T = (u16*)alloc(128ULL * 1024 * 2);
  u16* TW2T = (u16*)alloc(1024ULL * 64 * 2);
  u16* WRb  = (u16*)alloc(1048576ULL * 2);
  u16* WKb  = (u16*)alloc(1048576ULL * 2);
  u16* WVb  = (u16*)alloc(1048576ULL * 2);
  u16* WGb  = (u16*)alloc(1048576ULL * 2);
  u16* WOb  = (u16*)alloc(1048576ULL * 2);
  float* Ab = (float*)alloc(33554432ULL);   // [bh][c][64][64] f32
  float* Pg = (float*)alloc(524288ULL);     // [bh][c][64] f32

  u16*   XM = S1; u16* XW = S2; u16* XK = S3; u16* XV = S4; u16* XR = S5; u16* XG = S6;
  u16*   XBF = S7; u16* XX = S8;
  u16*   Rb = S1; u16* Kb = S7; u16* Vb = S8; u16* Gb = S9;
  u16*   Y   = S2;            // bf16 (xw dead after Hb gemm)
  float* DEC = (float*)S5;    // spans S5+S6 (xr,xg dead after rkvg gemm)
  float* Sg  = (float*)S7;    // spans S7+S8 (kb,vb dead after s1)
  u16*   Z   = S4;            // xv dead

  // allow 128KB dynamic LDS for the 256^2 kernels (idempotent, cheap)
  hipFuncSetAttribute(reinterpret_cast<const void*>(gemm256_k<0>),
                      hipFuncAttributeMaxDynamicSharedMemorySize, 131072);
  hipFuncSetAttribute(reinterpret_cast<const void*>(gemm256_k<1>),
                      hipFuncAttributeMaxDynamicSharedMemorySize, 131072);

  // weight casts / transposes (f32 -> bf16, [N][K] K-contiguous)
  Cast5P cp;
  cp.s[0]=WR; cp.s[1]=WK; cp.s[2]=WV; cp.s[3]=WG; cp.s[4]=WO;
  cp.d[0]=WRb; cp.d[1]=WKb; cp.d[2]=WVb; cp.d[3]=WGb; cp.d[4]=WOb;
  cast5_k<<<dim3(1024, 5), 256, 0, stream>>>(cp);
  tpad_k<<<1024, 256, 0, stream>>>(MW1, W1T, 1024, 160, 256LL * 1024);
  tpw2_k<<<640, 256, 0, stream>>>(MW2, W2T);
  tpad_k<<<512, 256, 0, stream>>>(TDW1, TW1T, 1024, 64, 128LL * 1024);
  tpad_k<<<256, 256, 0, stream>>>(TDW2, TW2T, 64, 1024, 1024LL * 64);

  // XM / XBF / XX
  mkxm_k<<<8192, 256, 0, stream>>>(X, TMX, XM, XBF, XX);

  // mix160 = tanh(XM @ maa_w1)        [8192,256(pad)]
  gemm_bt<1><<<dim3(64, 2), 256, 0, stream>>>(XM, 1024, W1T, 1024, MIXB, 256, 1024, nullptr);

  // x{w,k,v,r,g} = x + xx*(tm + mix_f @ maa_w2_f)   — one launch, z-loop inside
  Mix5P mp;
  mp.ex = XBF; mp.exx = XX;
  mp.out[0]=XW; mp.out[1]=XK; mp.out[2]=XV; mp.out[3]=XR; mp.out[4]=XG;
  mp.tm[0]=TMW; mp.tm[1]=TMK; mp.tm[2]=TMV; mp.tm[3]=TMR; mp.tm[4]=TMG;
  gemm_mix5<<<dim3(64, 8), 256, 0, stream>>>(MIXB, W2T, mp);

  // r, k, v, g — fused 256^2 pipelined (Rb over XM; Kb/Vb over XBF/XX — dead)
  G4P gp;
  gp.A[0]=XR; gp.A[1]=XK; gp.A[2]=XV; gp.A[3]=XG;
  gp.B[0]=WRb; gp.B[1]=WKb; gp.B[2]=WVb; gp.B[3]=WGb;
  gp.C[0]=Rb; gp.C[1]=Kb; gp.C[2]=Vb; gp.C[3]=Gb;
  gemm256_k<0><<<dim3(32, 4, 4), 512, 131072, stream>>>(gp, nullptr);

  // h = tanh(xw @ td_w1);  decay = exp(-exp(time_decay + h @ td_w2))
  gemm_bt<1><<<dim3(64, 1), 256, 0, stream>>>(XW, 1024, TW1T, 1024, Hb, 128, 1024, nullptr);
  gemm_bt<3><<<dim3(64, 8), 256, 0, stream>>>(Hb, 128, TW2T, 64, DEC, 1024, 64, TD);

  // WKV6 chunk-parallel scan (Y bf16)
  wkv_s1<<<2048, 256, 0, stream>>>(Rb, Kb, Vb, DEC, U, Y, Ab, Pg);
  wkv_s2<<<256, 256, 0, stream>>>(Ab, Pg, Sg);
  wkv_s3<<<2048, 256, 0, stream>>>(Rb, Sg, Y);

  // GroupNorm(y)*g -> z
  gnorm_k<<<8192, 256, 0, stream>>>(Y, Gb, LNG, LNB, Z);

  // out = z @ Wo^T   (f32 out, 256^2 pipelined)
  G4P go;
  go.A[0]=Z; go.B[0]=WOb; go.C[0]=nullptr;
  gemm256_k<1><<<dim3(32, 4, 1), 512, 131072, stream>>>(go, (float*)d_out);
}

// Round 8
// 359.249 us; speedup vs baseline: 1.0992x; 1.0992x over previous
//
#include <hip/hip_runtime.h>

typedef unsigned int u32;
typedef unsigned short u16;
typedef __attribute__((ext_vector_type(8))) short short8;
typedef __attribute__((ext_vector_type(4))) float f32x4;

__device__ __forceinline__ float b2f(u16 h){ u32 x = ((u32)h) << 16; return __builtin_bit_cast(float, x); }
__device__ __forceinline__ u16 f2b(float f){
  u32 x = __builtin_bit_cast(u32, f);
  x += 0x7fffu + ((x >> 16) & 1u);
  return (u16)(x >> 16);
}
#define LOH(u) ((u16)((u) & 0xffffu))
#define HIH(u) ((u16)((u) >> 16))

__device__ __forceinline__ void gload16(const u16* g, u16* lds){
  __builtin_amdgcn_global_load_lds((const __attribute__((address_space(1))) u32*)g,
                                   (__attribute__((address_space(3))) u32*)lds, 16, 0, 0);
}

// ---------------------------------------------------------------------------
// 256x256 8-wave deep-pipelined GEMM:  C = A[M,K] * B[N,K]^T, K=1024 fixed.
// BK=64, 512 threads (2x4 waves), double-buffered 128KB LDS, counted vmcnt(8),
// raw s_barrier, 4 phases/K-tile, setprio, T2 XOR-swizzle (chunk ^= row&7):
// source-side via pre-swizzled global column, read-side via XOR on chunk idx.
// MODE 0: bf16 out via gp.C[z] (z==3 -> SiLU).  MODE 1: f32 out via Cf.
// ---------------------------------------------------------------------------
struct G4P { const u16* A[4]; const u16* B[4]; u16* C[4]; };

template<int MODE>
__global__ __launch_bounds__(512, 2) void gemm256_k(G4P gp, float* __restrict__ Cf)
{
  extern __shared__ u16 lds[];   // [2][ A 16384 | B 16384 ] u16
  const int tid = threadIdx.x;
  const int z = blockIdx.z;
  const u16* __restrict__ A  = gp.A[z];
  const u16* __restrict__ Bw = gp.B[z];
  const int wid = tid >> 6, lane = tid & 63;
  const int wr = wid >> 2, wc = wid & 3;
  const int l16 = lane & 15, kq = lane >> 4;
  const int sw = l16 & 7;               // read-side swizzle key
  const long row0 = (long)blockIdx.x * 256;
  const long col0 = (long)blockIdx.y * 256;

  f32x4 acc[8][4];
#pragma unroll
  for (int i = 0; i < 8; i++)
#pragma unroll
    for (int j = 0; j < 4; j++) acc[i][j] = (f32x4)0.0f;

  // staging: chunk c = tid + it*512; row=c>>3 (+64/it), k8=(c&7).
  // Source-side swizzle: load global chunk (k8 ^ (row&7)) into linear LDS slot.
  const int srow = tid >> 3;
  const int sk8 = ((tid & 7) ^ (srow & 7)) * 8;
  const u16* Agp = A  + (row0 + srow) * 1024 + sk8;
  const u16* Bgp = Bw + (col0 + srow) * 1024 + sk8;

  auto STAGE = [&](int buf, int kt){
    u16* Ab = lds + buf * 32768;
    u16* Bb = Ab + 16384;
    const int ko = kt * 64;
#pragma unroll
    for (int it = 0; it < 4; it++){
      gload16(Agp + (long)it * 65536 + ko, Ab + (tid + it * 512) * 8);
      gload16(Bgp + (long)it * 65536 + ko, Bb + (tid + it * 512) * 8);
    }
  };

  STAGE(0, 0);
  const int NT = 16;   // K=1024 / BK=64
  for (int t = 0; t < NT; t++){
    const int cur = t & 1;
    if (t + 1 < NT){
      STAGE(cur ^ 1, t + 1);
      asm volatile("s_waitcnt vmcnt(8)" ::: "memory");   // tile t landed; t+1 in flight
    } else {
      asm volatile("s_waitcnt vmcnt(0)" ::: "memory");
    }
    __builtin_amdgcn_sched_barrier(0);
    __builtin_amdgcn_s_barrier();
    const u16* Ab = lds + cur * 32768;
    const u16* Bb = Ab + 16384;

    short8 afr[4][2], bfr0[2][2], bfr1[2][2];
    // ---- phase 0: quadrant (miH=0, niH=0) ----
#pragma unroll
    for (int mi = 0; mi < 4; mi++)
#pragma unroll
      for (int ks = 0; ks < 2; ks++)
        afr[mi][ks] = *(const short8*)&Ab[(wr*128 + mi*16 + l16)*64 + (((ks<<2)+kq) ^ sw)*8];
#pragma unroll
    for (int ni = 0; ni < 2; ni++)
#pragma unroll
      for (int ks = 0; ks < 2; ks++)
        bfr0[ni][ks] = *(const short8*)&Bb[(wc*64 + ni*16 + l16)*64 + (((ks<<2)+kq) ^ sw)*8];
    asm volatile("s_waitcnt lgkmcnt(0)" ::: "memory");
    __builtin_amdgcn_sched_barrier(0);
    __builtin_amdgcn_s_setprio(1);
#pragma unroll
    for (int mi = 0; mi < 4; mi++)
#pragma unroll
      for (int ni = 0; ni < 2; ni++)
#pragma unroll
        for (int ks = 0; ks < 2; ks++)
          acc[mi][ni] = __builtin_amdgcn_mfma_f32_16x16x32_bf16(afr[mi][ks], bfr0[ni][ks], acc[mi][ni], 0, 0, 0);
    __builtin_amdgcn_s_setprio(0);
    __builtin_amdgcn_s_barrier();
    // ---- phase 1: (0,1) ----
#pragma unroll
    for (int ni = 0; ni < 2; ni++)
#pragma unroll
      for (int ks = 0; ks < 2; ks++)
        bfr1[ni][ks] = *(const short8*)&Bb[(wc*64 + (2+ni)*16 + l16)*64 + (((ks<<2)+kq) ^ sw)*8];
    asm volatile("s_waitcnt lgkmcnt(0)" ::: "memory");
    __builtin_amdgcn_sched_barrier(0);
    __builtin_amdgcn_s_setprio(1);
#pragma unroll
    for (int mi = 0; mi < 4; mi++)
#pragma unroll
      for (int ni = 0; ni < 2; ni++)
#pragma unroll
        for (int ks = 0; ks < 2; ks++)
          acc[mi][2+ni] = __builtin_amdgcn_mfma_f32_16x16x32_bf16(afr[mi][ks], bfr1[ni][ks], acc[mi][2+ni], 0, 0, 0);
    __builtin_amdgcn_s_setprio(0);
    __builtin_amdgcn_s_barrier();
    // ---- phase 2: (1,0) ----
#pragma unroll
    for (int mi = 0; mi < 4; mi++)
#pragma unroll
      for (int ks = 0; ks < 2; ks++)
        afr[mi][ks] = *(const short8*)&Ab[(wr*128 + (4+mi)*16 + l16)*64 + (((ks<<2)+kq) ^ sw)*8];
    asm volatile("s_waitcnt lgkmcnt(0)" ::: "memory");
    __builtin_amdgcn_sched_barrier(0);
    __builtin_amdgcn_s_setprio(1);
#pragma unroll
    for (int mi = 0; mi < 4; mi++)
#pragma unroll
      for (int ni = 0; ni < 2; ni++)
#pragma unroll
        for (int ks = 0; ks < 2; ks++)
          acc[4+mi][ni] = __builtin_amdgcn_mfma_f32_16x16x32_bf16(afr[mi][ks], bfr0[ni][ks], acc[4+mi][ni], 0, 0, 0);
    __builtin_amdgcn_s_setprio(0);
    __builtin_amdgcn_s_barrier();
    // ---- phase 3: (1,1) — no LDS reads ----
    __builtin_amdgcn_s_setprio(1);
#pragma unroll
    for (int mi = 0; mi < 4; mi++)
#pragma unroll
      for (int ni = 0; ni < 2; ni++)
#pragma unroll
        for (int ks = 0; ks < 2; ks++)
          acc[4+mi][2+ni] = __builtin_amdgcn_mfma_f32_16x16x32_bf16(afr[mi][ks], bfr1[ni][ks], acc[4+mi][2+ni], 0, 0, 0);
    __builtin_amdgcn_s_setprio(0);
    __builtin_amdgcn_s_barrier();   // protects buf before next iter's STAGE overwrites
  }

  const bool SILU = (MODE == 0) && (z == 3);
#pragma unroll
  for (int mi = 0; mi < 8; mi++){
#pragma unroll
    for (int qq = 0; qq < 4; qq++){
      const long r = row0 + wr*128 + mi*16 + kq*4 + qq;
      if (MODE == 0){
        u16* crow = gp.C[z] + r * 1024 + col0 + wc*64 + l16;
#pragma unroll
        for (int ni = 0; ni < 4; ni++){
          float v = acc[mi][ni][qq];
          if (SILU) v = v / (1.0f + expf(-v));
          crow[ni * 16] = f2b(v);
        }
      } else {
        float* crow = Cf + r * 1024 + col0 + wc*64 + l16;
#pragma unroll
        for (int ni = 0; ni < 4; ni++)
          crow[ni * 16] = acc[mi][ni][qq];
      }
    }
  }
}

// ---------------------------------------------------------------------------
// Generic MFMA GEMM: C[M,N] = A[M,K] * B[N,K]^T   (A,B bf16 K-contiguous)
// 128x128 tile, BK=32, 256 threads (4 waves 2x2), 16x16x32 bf16 MFMA.
// EPI: 0 bf16, 1 tanh bf16, 3 decay f32 (e_vec), 4 silu bf16, 5 plain f32
// ---------------------------------------------------------------------------
template<int EPI>
__global__ __launch_bounds__(256) void gemm_bt(
    const u16* __restrict__ A, int lda,
    const u16* __restrict__ B, int ldb,
    void* __restrict__ Cv, int ldc, int K,
    const float* __restrict__ e_vec)
{
  __shared__ u16 As[4096];
  __shared__ u16 Bs[4096];
  const int tid = threadIdx.x;
  const int wave = tid >> 6, lane = tid & 63;
  const int wr = wave >> 1, wc = wave & 1;
  const int l16 = lane & 15, kq = lane >> 4;
  const long row0 = (long)blockIdx.x * 128;
  const long col0 = (long)blockIdx.y * 128;

  f32x4 acc[4][4];
#pragma unroll
  for (int i = 0; i < 4; i++)
#pragma unroll
    for (int j = 0; j < 4; j++) acc[i][j] = (f32x4)0.0f;

  const int c0 = tid, c1 = tid + 256;
  const u16* Ag0 = A + (row0 + (c0 >> 2)) * (long)lda + (c0 & 3) * 8;
  const u16* Ag1 = A + (row0 + (c1 >> 2)) * (long)lda + (c1 & 3) * 8;
  const u16* Bg0 = B + (col0 + (c0 >> 2)) * (long)ldb + (c0 & 3) * 8;
  const u16* Bg1 = B + (col0 + (c1 >> 2)) * (long)ldb + (c1 & 3) * 8;
  u16* Al0 = &As[c0 * 8]; u16* Al1 = &As[c1 * 8];
  u16* Bl0 = &Bs[c0 * 8]; u16* Bl1 = &Bs[c1 * 8];

  for (int kk = 0; kk < K; kk += 32){
    __syncthreads();
    gload16(Ag0 + kk, Al0);
    gload16(Ag1 + kk, Al1);
    gload16(Bg0 + kk, Bl0);
    gload16(Bg1 + kk, Bl1);
    __syncthreads();
    short8 af[4], bfr[4];
#pragma unroll
    for (int mi = 0; mi < 4; mi++) af[mi]  = *(const short8*)&As[(wr*64 + mi*16 + l16)*32 + kq*8];
#pragma unroll
    for (int ni = 0; ni < 4; ni++) bfr[ni] = *(const short8*)&Bs[(wc*64 + ni*16 + l16)*32 + kq*8];
#pragma unroll
    for (int mi = 0; mi < 4; mi++)
#pragma unroll
      for (int ni = 0; ni < 4; ni++)
        acc[mi][ni] = __builtin_amdgcn_mfma_f32_16x16x32_bf16(af[mi], bfr[ni], acc[mi][ni], 0, 0, 0);
  }

#pragma unroll
  for (int mi = 0; mi < 4; mi++){
#pragma unroll
    for (int qq = 0; qq < 4; qq++){
      const long r = row0 + wr*64 + mi*16 + kq*4 + qq;   // C/D: row=(lane>>4)*4+reg
#pragma unroll
      for (int ni = 0; ni < 4; ni++){
        const long c = col0 + wc*64 + ni*16 + l16;        //      col=lane&15
        const float v = acc[mi][ni][qq];
        if (EPI == 0){
          ((u16*)Cv)[r * ldc + c] = f2b(v);
        } else if (EPI == 1){
          ((u16*)Cv)[r * ldc + c] = f2b(tanhf(v));
        } else if (EPI == 3){
          const float w = v + e_vec[c];
          ((float*)Cv)[r * ldc + c] = expf(-expf(w));
        } else if (EPI == 4){
          ((u16*)Cv)[r * ldc + c] = f2b(v / (1.0f + expf(-v)));
        } else {
          ((float*)Cv)[r * ldc + c] = v;
        }
      }
    }
  }
}

// ---------------------------------------------------------------------------
// Fused 5-way token-mix GEMM, z-loop INSIDE: one block computes the 128x128
// tile for all 5 f's.  C_f = bf16( x + xx * (tm_f + MIXB_f @ W2T_f^T) ).
// A-tile [128][160] staged once (2560 16B chunks); ex/exx hoisted to regs.
// ---------------------------------------------------------------------------
struct Mix5P { const u16* ex; const u16* exx; u16* out[5]; const float* tm[5]; };

__global__ __launch_bounds__(256) void gemm_mix5(
    const u16* __restrict__ Am, const u16* __restrict__ W2T, Mix5P mp)
{
  __shared__ u16 As[128 * 160];   // 40 KB, stride 160
  __shared__ u16 Bs[128 * 32];    // 8 KB
  const int tid = threadIdx.x;
  const int wave = tid >> 6, lane = tid & 63;
  const int wr = wave >> 1, wc = wave & 1;
  const int l16 = lane & 15, kq = lane >> 4;
  const long row0 = (long)blockIdx.x * 128;
  const long col0 = (long)blockIdx.y * 128;

  // stage A-tile [128][160]: 160 u16/row = 20 chunks/row, 2560 chunks total.
#pragma unroll
  for (int it = 0; it < 10; it++){
    const int c = tid + it * 256;
    const int r = c / 20, c8 = c - r * 20;
    gload16(Am + (row0 + r) * 256 + c8 * 8, &As[c * 8]);
  }

  // hoisted ex/exx loads: 64 positions, packed (ex lo | exx hi)
  u32 pxx[64];
#pragma unroll
  for (int mi = 0; mi < 4; mi++)
#pragma unroll
    for (int qq = 0; qq < 4; qq++){
      const long r = row0 + wr*64 + mi*16 + kq*4 + qq;
#pragma unroll
      for (int ni = 0; ni < 4; ni++){
        const long c = col0 + wc*64 + ni*16 + l16;
        const u16 a = mp.ex[r * 1024 + c];
        const u16 b = mp.exx[r * 1024 + c];
        pxx[mi*16 + qq*4 + ni] = (u32)a | ((u32)b << 16);
      }
    }

  for (int z = 0; z < 5; z++){
    __syncthreads();
    const u16* B = W2T + z * 32768;
#pragma unroll
    for (int it = 0; it < 2; it++){
      const int c = tid + it * 256;
      gload16(B + (col0 + (c >> 2)) * 32 + (c & 3) * 8, &Bs[c * 8]);
    }
    __syncthreads();
    short8 af[4], bfr[4];
#pragma unroll
    for (int mi = 0; mi < 4; mi++) af[mi]  = *(const short8*)&As[(wr*64 + mi*16 + l16)*160 + z*32 + kq*8];
#pragma unroll
    for (int ni = 0; ni < 4; ni++) bfr[ni] = *(const short8*)&Bs[(wc*64 + ni*16 + l16)*32 + kq*8];
    f32x4 acc[4][4];
#pragma unroll
    for (int i = 0; i < 4; i++)
#pragma unroll
      for (int j = 0; j < 4; j++) acc[i][j] = (f32x4)0.0f;
#pragma unroll
    for (int mi = 0; mi < 4; mi++)
#pragma unroll
      for (int ni = 0; ni < 4; ni++)
        acc[mi][ni] = __builtin_amdgcn_mfma_f32_16x16x32_bf16(af[mi], bfr[ni], acc[mi][ni], 0, 0, 0);

    const float* tm = mp.tm[z];
    float tmv[4];
#pragma unroll
    for (int ni = 0; ni < 4; ni++) tmv[ni] = tm[col0 + wc*64 + ni*16 + l16];
    u16* C = mp.out[z];
#pragma unroll
    for (int mi = 0; mi < 4; mi++){
#pragma unroll
      for (int qq = 0; qq < 4; qq++){
        const long r = row0 + wr*64 + mi*16 + kq*4 + qq;
        u16* crow = C + r * 1024 + col0 + wc*64 + l16;
#pragma unroll
        for (int ni = 0; ni < 4; ni++){
          const u32 pk = pxx[mi*16 + qq*4 + ni];
          const float xc = b2f(LOH(pk));
          const float xx = b2f(HIH(pk));
          crow[ni * 16] = f2b(xc + xx * (tmv[ni] + acc[mi][ni][qq]));
        }
      }
    }
  }
}

// ---------------------------------------------------------------------------
// XM = bf16(x + (xp-x)*tmx);  XBF = bf16(x);  XX = bf16(xp - x)
// ---------------------------------------------------------------------------
__global__ __launch_bounds__(256) void mkxm_k(const float* __restrict__ X,
    const float* __restrict__ tmx, u16* __restrict__ XM,
    u16* __restrict__ XBF, u16* __restrict__ XXo)
{
  const long idx = (long)blockIdx.x * 256 + threadIdx.x;
  const long m = idx >> 8;
  const int c4 = (int)(idx & 255) * 4;
  const float4 x = *(const float4*)(X + m * 1024 + c4);
  float4 p = make_float4(0.f, 0.f, 0.f, 0.f);
  if ((m & 2047) != 0) p = *(const float4*)(X + (m - 1) * 1024 + c4);
  const float4 t = *(const float4*)(tmx + c4);
  ushort4 o;
  o.x = f2b(x.x + (p.x - x.x) * t.x);
  o.y = f2b(x.y + (p.y - x.y) * t.y);
  o.z = f2b(x.z + (p.z - x.z) * t.z);
  o.w = f2b(x.w + (p.w - x.w) * t.w);
  *(ushort4*)(XM + m * 1024 + c4) = o;
  ushort4 ob; ob.x = f2b(x.x); ob.y = f2b(x.y); ob.z = f2b(x.z); ob.w = f2b(x.w);
  *(ushort4*)(XBF + m * 1024 + c4) = ob;
  ushort4 ox; ox.x = f2b(p.x - x.x); ox.y = f2b(p.y - x.y); ox.z = f2b(p.z - x.z); ox.w = f2b(p.w - x.w);
  *(ushort4*)(XXo + m * 1024 + c4) = ox;
}

// ---------------------------------------------------------------------------
// 5 weight casts in one launch (blockIdx.y = which)
// ---------------------------------------------------------------------------
struct Cast5P { const float* s[5]; u16* d[5]; };
__global__ __launch_bounds__(256) void cast5_k(Cast5P cp)
{
  const int w = blockIdx.y;
  const long i = (long)blockIdx.x * 256 + threadIdx.x;
  const float4 v = ((const float4*)cp.s[w])[i];
  ushort4 o; o.x = f2b(v.x); o.y = f2b(v.y); o.z = f2b(v.z); o.w = f2b(v.w);
  ((ushort4*)cp.d[w])[i] = o;
}

// ---------------------------------------------------------------------------
// dst[n][k] = bf16( (n < Ccols) ? src[k][n] : 0 )   dst [dstR][R], idx = n*R+k
// ---------------------------------------------------------------------------
__global__ __launch_bounds__(256) void tpad_k(const float* __restrict__ src,
    u16* __restrict__ dst, int R, int Ccols, long total)
{
  const long idx = (long)blockIdx.x * 256 + threadIdx.x;
  if (idx >= total) return;
  const int k = (int)(idx % R);
  const int n = (int)(idx / R);
  dst[idx] = (n < Ccols) ? f2b(src[(long)k * Ccols + n]) : (u16)0;
}

// ---------------------------------------------------------------------------
// MW2 [5][32][1024] -> W2T [5][1024][32] bf16, one launch
// ---------------------------------------------------------------------------
__global__ __launch_bounds__(256) void tpw2_k(const float* __restrict__ src,
    u16* __restrict__ dst)
{
  const int n = blockIdx.x * 256 + threadIdx.x;    // < 163840
  const int k = n & 31;
  const int col = (n >> 5) & 1023;
  const int f = n >> 15;
  dst[n] = f2b(src[f * 32768 + k * 1024 + col]);
}

// ---------------------------------------------------------------------------
// WKV6 stage 1 (MFMA). Block per (b,h,chunk).
//  M = r̃·k̃ᵀ (masked s<i), Y = M·V + diag·v (bf16 out), A = k̃ᵀ·V, r̃ -> Rg, Pg.
// ---------------------------------------------------------------------------
__global__ __launch_bounds__(256) void wkv_s1(
    u16* __restrict__ Rg, const u16* __restrict__ Kg, const u16* __restrict__ Vg,
    const float* __restrict__ Dg, const float* __restrict__ Ug,
    u16* __restrict__ Yg, float* __restrict__ Ag, float* __restrict__ Pg)
{
  __shared__ u16 RT_[64 * 72];     // r -> r̃  [i][k]
  __shared__ u16 KT_[64 * 72];     // k -> k̃  [s][k]
  __shared__ u16 KTT_[64 * 72];    // k̃ᵀ [k][s]
  __shared__ u16 V_[64 * 72];      // V [s][j]
  __shared__ u16 VT_[64 * 72];     // Vᵀ [j][s]
  __shared__ char UD_[64 * 68 * 4];// D f32 [i][68], then M u16 [i][72]
  __shared__ float us_[64];
  __shared__ float dg4_[256];
  __shared__ float dg_[64];
  float* D_ = (float*)UD_;
  u16*  M_  = (u16*)UD_;

  const int tid = threadIdx.x;
  const int bh = blockIdx.x >> 5, ch = blockIdx.x & 31;
  const int b = bh >> 4, h = bh & 15, cb = h * 64;
  const long rowb = (long)b * 2048 + ch * 64;

  if (tid < 64) us_[tid] = Ug[cb + tid];

  const int iS = tid >> 2, sg = tid & 3;
  // ---- P0: stage r,k,v(,vT),d
  {
    const long go = (rowb + iS) * 1024 + cb + sg * 16;
    uint4 a0 = *(const uint4*)(Rg + go);
    uint4 a1 = *(const uint4*)(Rg + go + 8);
    u32* rd = (u32*)&RT_[iS * 72 + sg * 16];
    rd[0]=a0.x; rd[1]=a0.y; rd[2]=a0.z; rd[3]=a0.w;
    rd[4]=a1.x; rd[5]=a1.y; rd[6]=a1.z; rd[7]=a1.w;
    a0 = *(const uint4*)(Kg + go); a1 = *(const uint4*)(Kg + go + 8);
    u32* kd = (u32*)&KT_[iS * 72 + sg * 16];
    kd[0]=a0.x; kd[1]=a0.y; kd[2]=a0.z; kd[3]=a0.w;
    kd[4]=a1.x; kd[5]=a1.y; kd[6]=a1.z; kd[7]=a1.w;
    a0 = *(const uint4*)(Vg + go); a1 = *(const uint4*)(Vg + go + 8);
    u32* vd = (u32*)&V_[iS * 72 + sg * 16];
    vd[0]=a0.x; vd[1]=a0.y; vd[2]=a0.z; vd[3]=a0.w;
    vd[4]=a1.x; vd[5]=a1.y; vd[6]=a1.z; vd[7]=a1.w;
    const u32 vw[8] = {a0.x,a0.y,a0.z,a0.w,a1.x,a1.y,a1.z,a1.w};
#pragma unroll
    for (int e = 0; e < 8; e++){
      VT_[(sg*16 + 2*e    ) * 72 + iS] = LOH(vw[e]);
      VT_[(sg*16 + 2*e + 1) * 72 + iS] = HIH(vw[e]);
    }
    const float4* dsrc = (const float4*)(Dg + go);
    float4* dd = (float4*)&D_[iS * 68 + sg * 16];
    dd[0]=dsrc[0]; dd[1]=dsrc[1]; dd[2]=dsrc[2]; dd[3]=dsrc[3];
  }
  __syncthreads();
  // ---- P0b: diag partials with RAW r,k
  {
    const int i = tid & 63, q = tid >> 6;
    const u32* rr = (const u32*)&RT_[i * 72 + q * 16];
    const u32* kr = (const u32*)&KT_[i * 72 + q * 16];
    const float* up = &us_[q * 16];
    float ds = 0.0f;
#pragma unroll
    for (int e = 0; e < 8; e++){
      ds += b2f(LOH(rr[e])) * up[2*e]   * b2f(LOH(kr[e]));
      ds += b2f(HIH(rr[e])) * up[2*e+1] * b2f(HIH(kr[e]));
    }
    dg4_[i * 4 + q] = ds;
  }
  __syncthreads();
  // ---- P0c: prefix decay; RT->r̃, KT->k̃ (and KTT); diag finalize; Pg
  if (tid < 64){
    const int k = tid;
    dg_[k] = dg4_[k*4] + dg4_[k*4+1] + dg4_[k*4+2] + dg4_[k*4+3];
    float pz = 1.0f;
#pragma unroll 4
    for (int i = 0; i < 64; i++){
      const float d = D_[i * 68 + k];
      const int ro = i * 72 + k;
      RT_[ro] = f2b(b2f(RT_[ro]) * pz);
      pz *= d;
      const u16 kb = f2b(b2f(KT_[ro]) * (1.0f / pz));
      KT_[ro] = kb;
      KTT_[k * 72 + i] = kb;
    }
    Pg[((long)bh * 32 + ch) * 64 + k] = pz;
  }
  __syncthreads();
  // ---- writeback r̃ to Rg
  {
    const u32* rr = (const u32*)&RT_[iS * 72 + sg * 16];
    u32* out = (u32*)(Rg + (rowb + iS) * 1024 + cb + sg * 16);
#pragma unroll
    for (int e = 0; e < 8; e++) out[e] = rr[e];
  }
  const int wave = tid >> 6, lane = tid & 63;
  const int wr = wave >> 1, wc = wave & 1;
  const int l16 = lane & 15, kq = lane >> 4;
  // ---- P2: M = r̃·k̃ᵀ, mask s<i, store bf16 to M_
  {
    f32x4 acc[2][2];
#pragma unroll
    for (int a = 0; a < 2; a++)
#pragma unroll
      for (int c = 0; c < 2; c++) acc[a][c] = (f32x4)0.0f;
#pragma unroll
    for (int ks = 0; ks < 2; ks++){
      short8 af[2], bf[2];
#pragma unroll
      for (int mi = 0; mi < 2; mi++) af[mi] = *(const short8*)&RT_[(wr*32 + mi*16 + l16)*72 + ks*32 + kq*8];
#pragma unroll
      for (int ni = 0; ni < 2; ni++) bf[ni] = *(const short8*)&KT_[(wc*32 + ni*16 + l16)*72 + ks*32 + kq*8];
#pragma unroll
      for (int mi = 0; mi < 2; mi++)
#pragma unroll
        for (int ni = 0; ni < 2; ni++)
          acc[mi][ni] = __builtin_amdgcn_mfma_f32_16x16x32_bf16(af[mi], bf[ni], acc[mi][ni], 0, 0, 0);
    }
    __syncthreads();    // D_ dead; M_ union becomes valid
#pragma unroll
    for (int mi = 0; mi < 2; mi++)
#pragma unroll
      for (int ni = 0; ni < 2; ni++)
#pragma unroll
        for (int qq = 0; qq < 4; qq++){
          const int ii = wr*32 + mi*16 + kq*4 + qq;
          const int ss = wc*32 + ni*16 + l16;
          M_[ii * 72 + ss] = f2b(ss < ii ? acc[mi][ni][qq] : 0.0f);
        }
  }
  __syncthreads();
  // ---- P3+P4: Y = M·V + diag·v ; A = k̃ᵀ·V
  {
    f32x4 accY[2][2], accA[2][2];
#pragma unroll
    for (int a = 0; a < 2; a++)
#pragma unroll
      for (int c = 0; c < 2; c++){ accY[a][c] = (f32x4)0.0f; accA[a][c] = (f32x4)0.0f; }
#pragma unroll
    for (int ks = 0; ks < 2; ks++){
      short8 am[2], ak[2], bv[2];
#pragma unroll
      for (int mi = 0; mi < 2; mi++){
        am[mi] = *(const short8*)&M_[(wr*32 + mi*16 + l16)*72 + ks*32 + kq*8];
        ak[mi] = *(const short8*)&KTT_[(wr*32 + mi*16 + l16)*72 + ks*32 + kq*8];
      }
#pragma unroll
      for (int ni = 0; ni < 2; ni++) bv[ni] = *(const short8*)&VT_[(wc*32 + ni*16 + l16)*72 + ks*32 + kq*8];
#pragma unroll
      for (int mi = 0; mi < 2; mi++)
#pragma unroll
        for (int ni = 0; ni < 2; ni++){
          accY[mi][ni] = __builtin_amdgcn_mfma_f32_16x16x32_bf16(am[mi], bv[ni], accY[mi][ni], 0, 0, 0);
          accA[mi][ni] = __builtin_amdgcn_mfma_f32_16x16x32_bf16(ak[mi], bv[ni], accA[mi][ni], 0, 0, 0);
        }
    }
    float* abase = Ag + ((long)bh * 32 + ch) * 4096;
#pragma unroll
    for (int mi = 0; mi < 2; mi++)
#pragma unroll
      for (int qq = 0; qq < 4; qq++){
        const int ii = wr*32 + mi*16 + kq*4 + qq;
        u16* yrow = Yg + (rowb + ii) * 1024 + cb;
        float* arow = abase + ii * 64;
#pragma unroll
        for (int ni = 0; ni < 2; ni++){
          const int jj = wc*32 + ni*16 + l16;
          const float yv = accY[mi][ni][qq] + dg_[ii] * b2f(V_[ii * 72 + jj]);
          yrow[jj] = f2b(yv);
          arow[jj] = accA[mi][ni][qq];
        }
      }
  }
}

// ---------------------------------------------------------------------------
// WKV6 stage 2 — inter-chunk recurrence S_{c+1} = ps_c*(S_c + A_c).
// ---------------------------------------------------------------------------
__global__ __launch_bounds__(256) void wkv_s2(
    const float* __restrict__ Ag, const float* __restrict__ Pg, float* __restrict__ Sg)
{
  const int tid = threadIdx.x;
  const int bh = blockIdx.x >> 2, kq = blockIdx.x & 3;
  const int kk = tid >> 4, jo = tid & 15;
  const int krow = kq * 16 + kk;
  const long base = (long)bh * 32;
  float4 S = make_float4(0.f, 0.f, 0.f, 0.f);
  for (int c = 0; c < 32; c++){
    const long mo = (base + c) * 4096 + krow * 64 + jo * 4;
    *(float4*)(Sg + mo) = S;
    const float4 a = *(const float4*)(Ag + mo);
    const float ps = Pg[(base + c) * 64 + krow];
    S.x = ps * (S.x + a.x); S.y = ps * (S.y + a.y);
    S.z = ps * (S.z + a.z); S.w = ps * (S.w + a.w);
  }
}

// ---------------------------------------------------------------------------
// WKV6 stage 3 — cross term: Yg += rt~ . S_chunkstart (bf16 RMW).
// ---------------------------------------------------------------------------
__global__ __launch_bounds__(256) void wkv_s3(
    const u16* __restrict__ Rtg, const float* __restrict__ Sg, u16* __restrict__ Yg)
{
  __shared__ float Ss[4096];        // [k][j]
  __shared__ u16 RTs[64 * 66];
  const int tid = threadIdx.x;
  const int bh = blockIdx.x >> 5, ch = blockIdx.x & 31;
  if (ch == 0) return;
  const int b = bh >> 4, h = bh & 15, cb = h * 64;
  const long rowb = (long)b * 2048 + ch * 64;

  {
    const float4* sp = (const float4*)(Sg + ((long)bh * 32 + ch) * 4096);
    float4* sd = (float4*)Ss;
#pragma unroll
    for (int e = 0; e < 4; e++) sd[tid + e * 256] = sp[tid + e * 256];
  }
  {
    const int iS = tid >> 2, sg4 = tid & 3;
    const u32* src = (const u32*)(Rtg + (rowb + iS) * 1024 + cb + sg4 * 16);
    u32* dst = (u32*)&RTs[iS * 66 + sg4 * 16];
#pragma unroll
    for (int e = 0; e < 8; e++) dst[e] = src[e];
  }
  __syncthreads();

  const int i_ = tid & 63, q = tid >> 6, jb = q * 16;
  float rt[64];
  {
    const u32* rr = (const u32*)&RTs[i_ * 66];
#pragma unroll
    for (int kk = 0; kk < 32; kk++){
      const u32 u = rr[kk];
      rt[2*kk] = b2f(LOH(u)); rt[2*kk+1] = b2f(HIH(u));
    }
  }
  u16* yo = Yg + (rowb + i_) * 1024 + cb + jb;
  float y[16];
  {
    const u32* yp = (const u32*)yo;
#pragma unroll
    for (int j2 = 0; j2 < 8; j2++){
      const u32 u = yp[j2];
      y[2*j2] = b2f(LOH(u)); y[2*j2+1] = b2f(HIH(u));
    }
  }
#pragma unroll
  for (int k = 0; k < 64; k++){
    const float rk = rt[k];
    const float4* sr = (const float4*)&Ss[k * 64 + jb];
#pragma unroll
    for (int j4 = 0; j4 < 4; j4++){
      const float4 sv = sr[j4];
      y[4*j4+0] += rk*sv.x; y[4*j4+1] += rk*sv.y; y[4*j4+2] += rk*sv.z; y[4*j4+3] += rk*sv.w;
    }
  }
  {
    u32* yp = (u32*)yo;
#pragma unroll
    for (int j2 = 0; j2 < 8; j2++)
      yp[j2] = (u32)f2b(y[2*j2]) | ((u32)f2b(y[2*j2+1]) << 16);
  }
}

// ---------------------------------------------------------------------------
// GroupNorm over each head's 64 channels, then * g   (one block per bt row)
// ---------------------------------------------------------------------------
__global__ __launch_bounds__(256) void gnorm_k(const u16* __restrict__ Y,
    const u16* __restrict__ G, const float* __restrict__ lng,
    const float* __restrict__ lnb, u16* __restrict__ Z)
{
  const long row = blockIdx.x;
  const int tid = threadIdx.x;
  const int hh = tid >> 4, l = tid & 15;
  const int c = hh * 64 + l * 4;
  const u32* yp = (const u32*)(Y + row * 1024 + c);
  const u32 y01 = yp[0], y23 = yp[1];
  const float vv[4] = {b2f(LOH(y01)), b2f(HIH(y01)), b2f(LOH(y23)), b2f(HIH(y23))};
  float s = vv[0] + vv[1] + vv[2] + vv[3];
  float sq = vv[0]*vv[0] + vv[1]*vv[1] + vv[2]*vv[2] + vv[3]*vv[3];
#pragma unroll
  for (int off = 1; off < 16; off <<= 1){ s += __shfl_xor(s, off); sq += __shfl_xor(sq, off); }
  const float mean = s * 0.015625f;
  const float var = sq * 0.015625f - mean * mean;
  const float rstd = rsqrtf(var + 6.4e-4f);   // eps = 1e-5 * 64
  const uint2 gg = *(const uint2*)(G + row * 1024 + c);
  const float4 lg = *(const float4*)(lng + c);
  const float4 lb = *(const float4*)(lnb + c);
  const float lgs[4] = {lg.x, lg.y, lg.z, lg.w};
  const float lbs[4] = {lb.x, lb.y, lb.z, lb.w};
  const u32 gs[2] = {gg.x, gg.y};
  ushort4 o;
  u16* op = (u16*)&o;
#pragma unroll
  for (int e = 0; e < 4; e++){
    const float gv = b2f((e & 1) ? HIH(gs[e >> 1]) : LOH(gs[e >> 1]));
    op[e] = f2b(((vv[e] - mean) * rstd * lgs[e] + lbs[e]) * gv);
  }
  *(ushort4*)(Z + row * 1024 + c) = o;
}

// ---------------------------------------------------------------------------
extern "C" void kernel_launch(void* const* d_in, const int* in_sizes, int n_in,
                              void* d_out, int out_size, void* d_ws, size_t ws_size,
                              hipStream_t stream)
{
  (void)in_sizes; (void)n_in; (void)out_size; (void)ws_size;
  const float* X    = (const float*)d_in[0];
  const float* TMX  = (const float*)d_in[1];
  const float* TMW  = (const float*)d_in[2];
  const float* TMK  = (const float*)d_in[3];
  const float* TMV  = (const float*)d_in[4];
  const float* TMR  = (const float*)d_in[5];
  const float* TMG  = (const float*)d_in[6];
  const float* MW1  = (const float*)d_in[7];
  const float* MW2  = (const float*)d_in[8];
  const float* TD   = (const float*)d_in[9];
  const float* TDW1 = (const float*)d_in[10];
  const float* TDW2 = (const float*)d_in[11];
  const float* U    = (const float*)d_in[12];
  const float* WR   = (const float*)d_in[13];
  const float* WK   = (const float*)d_in[14];
  const float* WV   = (const float*)d_in[15];
  const float* WG   = (const float*)d_in[16];
  const float* WO   = (const float*)d_in[17];
  const float* LNG  = (const float*)d_in[18];
  const float* LNB  = (const float*)d_in[19];

  char* ws = (char*)d_ws;
  const size_t SLOT = 16777216ULL;     // B*T*C bf16 bytes
  u16* S1 = (u16*)(ws + 0 * SLOT);     // XM  -> Rb (-> rt~)
  u16* S2 = (u16*)(ws + 1 * SLOT);     // XW  -> Y (bf16)
  u16* S3 = (u16*)(ws + 2 * SLOT);     // XK
  u16* S4 = (u16*)(ws + 3 * SLOT);     // XV  -> Z
  u16* S5 = (u16*)(ws + 4 * SLOT);     // XR  -> DEC lo
  u16* S6 = (u16*)(ws + 5 * SLOT);     // XG  -> DEC hi
  u16* S7 = (u16*)(ws + 6 * SLOT);     // XBF -> Kb -> Sg lo
  u16* S8 = (u16*)(ws + 7 * SLOT);     // XX  -> Vb -> Sg hi
  u16* S9 = (u16*)(ws + 8 * SLOT);     // Gb
  char* p = ws + 9 * SLOT;
  auto alloc = [&](size_t bytes) -> void* {
    void* q = p; p += (bytes + 255) & ~(size_t)255; return q;
  };
  u16* MIXB = (u16*)alloc(8192ULL * 256 * 2);
  u16* Hb   = (u16*)alloc(8192ULL * 128 * 2);
  u16* W1T  = (u16*)alloc(256ULL * 1024 * 2);
  u16* W2T  = (u16*)alloc(5ULL * 1024 * 32 * 2);
  u16* TW1T = (u16*)alloc(128ULL * 1024 * 2);
  u16* TW2T = (u16*)alloc(1024ULL * 64 * 2);
  u16* WRb  = (u16*)alloc(1048576ULL * 2);
  u16* WKb  = (u16*)alloc(1048576ULL * 2);
  u16* WVb  = (u16*)alloc(1048576ULL * 2);
  u16* WGb  = (u16*)alloc(1048576ULL * 2);
  u16* WOb  = (u16*)alloc(1048576ULL * 2);
  float* Ab = (float*)alloc(33554432ULL);   // [bh][c][64][64] f32
  float* Pg = (float*)alloc(524288ULL);     // [bh][c][64] f32

  u16*   XM = S1; u16* XW = S2; u16* XK = S3; u16* XV = S4; u16* XR = S5; u16* XG = S6;
  u16*   XBF = S7; u16* XX = S8;
  u16*   Rb = S1; u16* Kb = S7; u16* Vb = S8; u16* Gb = S9;
  u16*   Y   = S2;            // bf16 (xw dead after Hb gemm)
  float* DEC = (float*)S5;    // spans S5+S6 (xr,xg dead after rkvg gemm)
  float* Sg  = (float*)S7;    // spans S7+S8 (kb,vb dead after s1)
  u16*   Z   = S4;            // xv dead

  // allow 128KB dynamic LDS for the 256^2 kernels (idempotent, cheap)
  hipFuncSetAttribute(reinterpret_cast<const void*>(gemm256_k<0>),
                      hipFuncAttributeMaxDynamicSharedMemorySize, 131072);
  hipFuncSetAttribute(reinterpret_cast<const void*>(gemm256_k<1>),
                      hipFuncAttributeMaxDynamicSharedMemorySize, 131072);

  // weight casts / transposes (f32 -> bf16, [N][K] K-contiguous)
  Cast5P cp;
  cp.s[0]=WR; cp.s[1]=WK; cp.s[2]=WV; cp.s[3]=WG; cp.s[4]=WO;
  cp.d[0]=WRb; cp.d[1]=WKb; cp.d[2]=WVb; cp.d[3]=WGb; cp.d[4]=WOb;
  cast5_k<<<dim3(1024, 5), 256, 0, stream>>>(cp);
  tpad_k<<<1024, 256, 0, stream>>>(MW1, W1T, 1024, 160, 256LL * 1024);
  tpw2_k<<<640, 256, 0, stream>>>(MW2, W2T);
  tpad_k<<<512, 256, 0, stream>>>(TDW1, TW1T, 1024, 64, 128LL * 1024);
  tpad_k<<<256, 256, 0, stream>>>(TDW2, TW2T, 64, 1024, 1024LL * 64);

  // XM / XBF / XX
  mkxm_k<<<8192, 256, 0, stream>>>(X, TMX, XM, XBF, XX);

  // mix160 = tanh(XM @ maa_w1)        [8192,256(pad)]
  gemm_bt<1><<<dim3(64, 2), 256, 0, stream>>>(XM, 1024, W1T, 1024, MIXB, 256, 1024, nullptr);

  // x{w,k,v,r,g} = x + xx*(tm + mix_f @ maa_w2_f)   — one launch, z-loop inside
  Mix5P mp;
  mp.ex = XBF; mp.exx = XX;
  mp.out[0]=XW; mp.out[1]=XK; mp.out[2]=XV; mp.out[3]=XR; mp.out[4]=XG;
  mp.tm[0]=TMW; mp.tm[1]=TMK; mp.tm[2]=TMV; mp.tm[3]=TMR; mp.tm[4]=TMG;
  gemm_mix5<<<dim3(64, 8), 256, 0, stream>>>(MIXB, W2T, mp);

  // r, k, v, g — fused 256^2 pipelined + swizzle (Rb over XM; Kb/Vb over XBF/XX)
  G4P gp;
  gp.A[0]=XR; gp.A[1]=XK; gp.A[2]=XV; gp.A[3]=XG;
  gp.B[0]=WRb; gp.B[1]=WKb; gp.B[2]=WVb; gp.B[3]=WGb;
  gp.C[0]=Rb; gp.C[1]=Kb; gp.C[2]=Vb; gp.C[3]=Gb;
  gemm256_k<0><<<dim3(32, 4, 4), 512, 131072, stream>>>(gp, nullptr);

  // h = tanh(xw @ td_w1);  decay = exp(-exp(time_decay + h @ td_w2))
  gemm_bt<1><<<dim3(64, 1), 256, 0, stream>>>(XW, 1024, TW1T, 1024, Hb, 128, 1024, nullptr);
  gemm_bt<3><<<dim3(64, 8), 256, 0, stream>>>(Hb, 128, TW2T, 64, DEC, 1024, 64, TD);

  // WKV6 chunk-parallel scan (Y bf16)
  wkv_s1<<<2048, 256, 0, stream>>>(Rb, Kb, Vb, DEC, U, Y, Ab, Pg);
  wkv_s2<<<256, 256, 0, stream>>>(Ab, Pg, Sg);
  wkv_s3<<<2048, 256, 0, stream>>>(Rb, Sg, Y);

  // GroupNorm(y)*g -> z
  gnorm_k<<<8192, 256, 0, stream>>>(Y, Gb, LNG, LNB, Z);

  // out = z @ Wo^T   (f32 out, 256^2 pipelined + swizzle)
  G4P go;
  go.A[0]=Z; go.B[0]=WOb; go.C[0]=nullptr;
  gemm256_k<1><<<dim3(32, 4, 1), 512, 131072, stream>>>(go, (float*)d_out);
}

// Round 9
// 350.580 us; speedup vs baseline: 1.1264x; 1.0247x over previous
//
#include <hip/hip_runtime.h>

typedef unsigned int u32;
typedef unsigned short u16;
typedef __attribute__((ext_vector_type(8))) short short8;
typedef __attribute__((ext_vector_type(4))) float f32x4;

__device__ __forceinline__ float b2f(u16 h){ u32 x = ((u32)h) << 16; return __builtin_bit_cast(float, x); }
__device__ __forceinline__ u16 f2b(float f){
  u32 x = __builtin_bit_cast(u32, f);
  x += 0x7fffu + ((x >> 16) & 1u);
  return (u16)(x >> 16);
}
#define LOH(u) ((u16)((u) & 0xffffu))
#define HIH(u) ((u16)((u) >> 16))

__device__ __forceinline__ void gload16(const u16* g, u16* lds){
  __builtin_amdgcn_global_load_lds((const __attribute__((address_space(1))) u32*)g,
                                   (__attribute__((address_space(3))) u32*)lds, 16, 0, 0);
}

// ---------------------------------------------------------------------------
// 256x256 8-wave GEMM, deep pipeline:  C = A[M,K] * B[N,K]^T, K=1024 fixed.
// BK=32, 4-deep LDS ring (4 x 32KB = 128KB), prefetch 2 tiles ahead,
// counted vmcnt(8) never draining in steady state, ONE barrier per tile,
// compiler-scheduled fine lgkm waits, T2 swizzle (chunk ^ ((row>>1)&3)),
// setprio around the MFMA cluster.
// MODE 0: bf16 out via gp.C[z] (z==3 -> SiLU).  MODE 1: f32 out via Cf.
// ---------------------------------------------------------------------------
struct G4P { const u16* A[4]; const u16* B[4]; u16* C[4]; };

template<int MODE>
__global__ __launch_bounds__(512, 2) void gemm256_k(G4P gp, float* __restrict__ Cf)
{
  extern __shared__ u16 lds[];   // 4 bufs x (A 8192 | B 8192) u16
  const int tid = threadIdx.x;
  const int z = blockIdx.z;
  const u16* __restrict__ A  = gp.A[z];
  const u16* __restrict__ Bw = gp.B[z];
  const int wid = tid >> 6, lane = tid & 63;
  const int wr = wid >> 2, wc = wid & 3;
  const int l16 = lane & 15, kq = lane >> 4;
  const int swr = (l16 >> 1) & 3;       // read-side swizzle key
  const long row0 = (long)blockIdx.x * 256;
  const long col0 = (long)blockIdx.y * 256;

  f32x4 acc[8][4];
#pragma unroll
  for (int i = 0; i < 8; i++)
#pragma unroll
    for (int j = 0; j < 4; j++) acc[i][j] = (f32x4)0.0f;

  // staging: per tile 4 gloads/thread (2 A + 2 B). LDS chunk c = tid + it*512;
  // (row, kpos) = (c>>2, c&3); source k-chunk = kpos ^ ((row>>1)&3)
  //             = (tid&3) ^ ((tid>>3)&3)  — invariant across it (it adds 128 rows).
  const int srow = tid >> 2;
  const int sk8 = ((tid & 3) ^ ((tid >> 3) & 3)) * 8;
  const u16* Agp = A  + (row0 + srow) * 1024 + sk8;
  const u16* Bgp = Bw + (col0 + srow) * 1024 + sk8;

  auto STAGE = [&](int buf, int kt){
    u16* Ab = lds + buf * 16384;
    u16* Bb = Ab + 8192;
    const int ko = kt * 32;
    gload16(Agp + ko,          Ab + tid * 8);
    gload16(Agp + 131072 + ko, Ab + (tid + 512) * 8);   // +128 rows
    gload16(Bgp + ko,          Bb + tid * 8);
    gload16(Bgp + 131072 + ko, Bb + (tid + 512) * 8);
  };

  STAGE(0, 0);
  STAGE(1, 1);
  const int NT = 32;   // K=1024 / BK=32
  for (int t = 0; t < NT; t++){
    const int cur = t & 3;
    if (t + 2 < NT) STAGE((t + 2) & 3, t + 2);
    if (t + 2 < NT)      { asm volatile("s_waitcnt vmcnt(8)" ::: "memory"); }
    else if (t + 1 < NT) { asm volatile("s_waitcnt vmcnt(4)" ::: "memory"); }
    else                 { asm volatile("s_waitcnt vmcnt(0)" ::: "memory"); }
    __builtin_amdgcn_sched_barrier(0);
    __builtin_amdgcn_s_barrier();      // all waves' tile-t loads landed
    __builtin_amdgcn_sched_barrier(0);
    const u16* Ab = lds + cur * 16384;
    const u16* Bb = Ab + 8192;
    short8 afr[8], bfr[4];
#pragma unroll
    for (int ni = 0; ni < 4; ni++)
      bfr[ni] = *(const short8*)&Bb[(wc*64 + ni*16 + l16)*32 + (kq ^ swr)*8];
#pragma unroll
    for (int mi = 0; mi < 8; mi++)
      afr[mi] = *(const short8*)&Ab[(wr*128 + mi*16 + l16)*32 + (kq ^ swr)*8];
    __builtin_amdgcn_s_setprio(1);
#pragma unroll
    for (int mi = 0; mi < 8; mi++)
#pragma unroll
      for (int ni = 0; ni < 4; ni++)
        acc[mi][ni] = __builtin_amdgcn_mfma_f32_16x16x32_bf16(afr[mi], bfr[ni], acc[mi][ni], 0, 0, 0);
    __builtin_amdgcn_s_setprio(0);
  }

  const bool SILU = (MODE == 0) && (z == 3);
#pragma unroll
  for (int mi = 0; mi < 8; mi++){
#pragma unroll
    for (int qq = 0; qq < 4; qq++){
      const long r = row0 + wr*128 + mi*16 + kq*4 + qq;
      if (MODE == 0){
        u16* crow = gp.C[z] + r * 1024 + col0 + wc*64 + l16;
#pragma unroll
        for (int ni = 0; ni < 4; ni++){
          float v = acc[mi][ni][qq];
          if (SILU) v = v / (1.0f + expf(-v));
          crow[ni * 16] = f2b(v);
        }
      } else {
        float* crow = Cf + r * 1024 + col0 + wc*64 + l16;
#pragma unroll
        for (int ni = 0; ni < 4; ni++)
          crow[ni * 16] = acc[mi][ni][qq];
      }
    }
  }
}

// ---------------------------------------------------------------------------
// Generic MFMA GEMM: C[M,N] = A[M,K] * B[N,K]^T   (A,B bf16 K-contiguous)
// 128x128 tile, BK=32, 256 threads (4 waves 2x2), 16x16x32 bf16 MFMA.
// EPI: 0 bf16, 1 tanh bf16, 3 decay f32 (e_vec), 4 silu bf16, 5 plain f32
// ---------------------------------------------------------------------------
template<int EPI>
__global__ __launch_bounds__(256) void gemm_bt(
    const u16* __restrict__ A, int lda,
    const u16* __restrict__ B, int ldb,
    void* __restrict__ Cv, int ldc, int K,
    const float* __restrict__ e_vec)
{
  __shared__ u16 As[4096];
  __shared__ u16 Bs[4096];
  const int tid = threadIdx.x;
  const int wave = tid >> 6, lane = tid & 63;
  const int wr = wave >> 1, wc = wave & 1;
  const int l16 = lane & 15, kq = lane >> 4;
  const long row0 = (long)blockIdx.x * 128;
  const long col0 = (long)blockIdx.y * 128;

  f32x4 acc[4][4];
#pragma unroll
  for (int i = 0; i < 4; i++)
#pragma unroll
    for (int j = 0; j < 4; j++) acc[i][j] = (f32x4)0.0f;

  const int c0 = tid, c1 = tid + 256;
  const u16* Ag0 = A + (row0 + (c0 >> 2)) * (long)lda + (c0 & 3) * 8;
  const u16* Ag1 = A + (row0 + (c1 >> 2)) * (long)lda + (c1 & 3) * 8;
  const u16* Bg0 = B + (col0 + (c0 >> 2)) * (long)ldb + (c0 & 3) * 8;
  const u16* Bg1 = B + (col0 + (c1 >> 2)) * (long)ldb + (c1 & 3) * 8;
  u16* Al0 = &As[c0 * 8]; u16* Al1 = &As[c1 * 8];
  u16* Bl0 = &Bs[c0 * 8]; u16* Bl1 = &Bs[c1 * 8];

  for (int kk = 0; kk < K; kk += 32){
    __syncthreads();
    gload16(Ag0 + kk, Al0);
    gload16(Ag1 + kk, Al1);
    gload16(Bg0 + kk, Bl0);
    gload16(Bg1 + kk, Bl1);
    __syncthreads();
    short8 af[4], bfr[4];
#pragma unroll
    for (int mi = 0; mi < 4; mi++) af[mi]  = *(const short8*)&As[(wr*64 + mi*16 + l16)*32 + kq*8];
#pragma unroll
    for (int ni = 0; ni < 4; ni++) bfr[ni] = *(const short8*)&Bs[(wc*64 + ni*16 + l16)*32 + kq*8];
#pragma unroll
    for (int mi = 0; mi < 4; mi++)
#pragma unroll
      for (int ni = 0; ni < 4; ni++)
        acc[mi][ni] = __builtin_amdgcn_mfma_f32_16x16x32_bf16(af[mi], bfr[ni], acc[mi][ni], 0, 0, 0);
  }

#pragma unroll
  for (int mi = 0; mi < 4; mi++){
#pragma unroll
    for (int qq = 0; qq < 4; qq++){
      const long r = row0 + wr*64 + mi*16 + kq*4 + qq;   // C/D: row=(lane>>4)*4+reg
#pragma unroll
      for (int ni = 0; ni < 4; ni++){
        const long c = col0 + wc*64 + ni*16 + l16;        //      col=lane&15
        const float v = acc[mi][ni][qq];
        if (EPI == 0){
          ((u16*)Cv)[r * ldc + c] = f2b(v);
        } else if (EPI == 1){
          ((u16*)Cv)[r * ldc + c] = f2b(tanhf(v));
        } else if (EPI == 3){
          const float w = v + e_vec[c];
          ((float*)Cv)[r * ldc + c] = expf(-expf(w));
        } else if (EPI == 4){
          ((u16*)Cv)[r * ldc + c] = f2b(v / (1.0f + expf(-v)));
        } else {
          ((float*)Cv)[r * ldc + c] = v;
        }
      }
    }
  }
}

// ---------------------------------------------------------------------------
// Fused 5-way token-mix GEMM, z-loop INSIDE: one block computes the 128x128
// tile for all 5 f's.  C_f = bf16( x + xx * (tm_f + MIXB_f @ W2T_f^T) ).
// A-tile [128][160] staged once (2560 16B chunks); ex/exx hoisted to regs.
// ---------------------------------------------------------------------------
struct Mix5P { const u16* ex; const u16* exx; u16* out[5]; const float* tm[5]; };

__global__ __launch_bounds__(256) void gemm_mix5(
    const u16* __restrict__ Am, const u16* __restrict__ W2T, Mix5P mp)
{
  __shared__ u16 As[128 * 160];   // 40 KB, stride 160
  __shared__ u16 Bs[128 * 32];    // 8 KB
  const int tid = threadIdx.x;
  const int wave = tid >> 6, lane = tid & 63;
  const int wr = wave >> 1, wc = wave & 1;
  const int l16 = lane & 15, kq = lane >> 4;
  const long row0 = (long)blockIdx.x * 128;
  const long col0 = (long)blockIdx.y * 128;

  // stage A-tile [128][160]: 160 u16/row = 20 chunks/row, 2560 chunks total.
#pragma unroll
  for (int it = 0; it < 10; it++){
    const int c = tid + it * 256;
    const int r = c / 20, c8 = c - r * 20;
    gload16(Am + (row0 + r) * 256 + c8 * 8, &As[c * 8]);
  }

  // hoisted ex/exx loads: 64 positions, packed (ex lo | exx hi)
  u32 pxx[64];
#pragma unroll
  for (int mi = 0; mi < 4; mi++)
#pragma unroll
    for (int qq = 0; qq < 4; qq++){
      const long r = row0 + wr*64 + mi*16 + kq*4 + qq;
#pragma unroll
      for (int ni = 0; ni < 4; ni++){
        const long c = col0 + wc*64 + ni*16 + l16;
        const u16 a = mp.ex[r * 1024 + c];
        const u16 b = mp.exx[r * 1024 + c];
        pxx[mi*16 + qq*4 + ni] = (u32)a | ((u32)b << 16);
      }
    }

  for (int z = 0; z < 5; z++){
    __syncthreads();
    const u16* B = W2T + z * 32768;
#pragma unroll
    for (int it = 0; it < 2; it++){
      const int c = tid + it * 256;
      gload16(B + (col0 + (c >> 2)) * 32 + (c & 3) * 8, &Bs[c * 8]);
    }
    __syncthreads();
    short8 af[4], bfr[4];
#pragma unroll
    for (int mi = 0; mi < 4; mi++) af[mi]  = *(const short8*)&As[(wr*64 + mi*16 + l16)*160 + z*32 + kq*8];
#pragma unroll
    for (int ni = 0; ni < 4; ni++) bfr[ni] = *(const short8*)&Bs[(wc*64 + ni*16 + l16)*32 + kq*8];
    f32x4 acc[4][4];
#pragma unroll
    for (int i = 0; i < 4; i++)
#pragma unroll
      for (int j = 0; j < 4; j++) acc[i][j] = (f32x4)0.0f;
#pragma unroll
    for (int mi = 0; mi < 4; mi++)
#pragma unroll
      for (int ni = 0; ni < 4; ni++)
        acc[mi][ni] = __builtin_amdgcn_mfma_f32_16x16x32_bf16(af[mi], bfr[ni], acc[mi][ni], 0, 0, 0);

    const float* tm = mp.tm[z];
    float tmv[4];
#pragma unroll
    for (int ni = 0; ni < 4; ni++) tmv[ni] = tm[col0 + wc*64 + ni*16 + l16];
    u16* C = mp.out[z];
#pragma unroll
    for (int mi = 0; mi < 4; mi++){
#pragma unroll
      for (int qq = 0; qq < 4; qq++){
        const long r = row0 + wr*64 + mi*16 + kq*4 + qq;
        u16* crow = C + r * 1024 + col0 + wc*64 + l16;
#pragma unroll
        for (int ni = 0; ni < 4; ni++){
          const u32 pk = pxx[mi*16 + qq*4 + ni];
          const float xc = b2f(LOH(pk));
          const float xx = b2f(HIH(pk));
          crow[ni * 16] = f2b(xc + xx * (tmv[ni] + acc[mi][ni][qq]));
        }
      }
    }
  }
}

// ---------------------------------------------------------------------------
// XM = bf16(x + (xp-x)*tmx);  XBF = bf16(x);  XX = bf16(xp - x)
// ---------------------------------------------------------------------------
__global__ __launch_bounds__(256) void mkxm_k(const float* __restrict__ X,
    const float* __restrict__ tmx, u16* __restrict__ XM,
    u16* __restrict__ XBF, u16* __restrict__ XXo)
{
  const long idx = (long)blockIdx.x * 256 + threadIdx.x;
  const long m = idx >> 8;
  const int c4 = (int)(idx & 255) * 4;
  const float4 x = *(const float4*)(X + m * 1024 + c4);
  float4 p = make_float4(0.f, 0.f, 0.f, 0.f);
  if ((m & 2047) != 0) p = *(const float4*)(X + (m - 1) * 1024 + c4);
  const float4 t = *(const float4*)(tmx + c4);
  ushort4 o;
  o.x = f2b(x.x + (p.x - x.x) * t.x);
  o.y = f2b(x.y + (p.y - x.y) * t.y);
  o.z = f2b(x.z + (p.z - x.z) * t.z);
  o.w = f2b(x.w + (p.w - x.w) * t.w);
  *(ushort4*)(XM + m * 1024 + c4) = o;
  ushort4 ob; ob.x = f2b(x.x); ob.y = f2b(x.y); ob.z = f2b(x.z); ob.w = f2b(x.w);
  *(ushort4*)(XBF + m * 1024 + c4) = ob;
  ushort4 ox; ox.x = f2b(p.x - x.x); ox.y = f2b(p.y - x.y); ox.z = f2b(p.z - x.z); ox.w = f2b(p.w - x.w);
  *(ushort4*)(XXo + m * 1024 + c4) = ox;
}

// ---------------------------------------------------------------------------
// 5 weight casts in one launch (blockIdx.y = which)
// ---------------------------------------------------------------------------
struct Cast5P { const float* s[5]; u16* d[5]; };
__global__ __launch_bounds__(256) void cast5_k(Cast5P cp)
{
  const int w = blockIdx.y;
  const long i = (long)blockIdx.x * 256 + threadIdx.x;
  const float4 v = ((const float4*)cp.s[w])[i];
  ushort4 o; o.x = f2b(v.x); o.y = f2b(v.y); o.z = f2b(v.z); o.w = f2b(v.w);
  ((ushort4*)cp.d[w])[i] = o;
}

// ---------------------------------------------------------------------------
// dst[n][k] = bf16( (n < Ccols) ? src[k][n] : 0 )   dst [dstR][R], idx = n*R+k
// ---------------------------------------------------------------------------
__global__ __launch_bounds__(256) void tpad_k(const float* __restrict__ src,
    u16* __restrict__ dst, int R, int Ccols, long total)
{
  const long idx = (long)blockIdx.x * 256 + threadIdx.x;
  if (idx >= total) return;
  const int k = (int)(idx % R);
  const int n = (int)(idx / R);
  dst[idx] = (n < Ccols) ? f2b(src[(long)k * Ccols + n]) : (u16)0;
}

// ---------------------------------------------------------------------------
// MW2 [5][32][1024] -> W2T [5][1024][32] bf16, one launch
// ---------------------------------------------------------------------------
__global__ __launch_bounds__(256) void tpw2_k(const float* __restrict__ src,
    u16* __restrict__ dst)
{
  const int n = blockIdx.x * 256 + threadIdx.x;    // < 163840
  const int k = n & 31;
  const int col = (n >> 5) & 1023;
  const int f = n >> 15;
  dst[n] = f2b(src[f * 32768 + k * 1024 + col]);
}

// ---------------------------------------------------------------------------
// WKV6 stage 1 (MFMA). Block per (b,h,chunk).
//  M = r̃·k̃ᵀ (masked s<i), Y = M·V + diag·v (bf16 out), A = k̃ᵀ·V, r̃ -> Rg, Pg.
// ---------------------------------------------------------------------------
__global__ __launch_bounds__(256) void wkv_s1(
    u16* __restrict__ Rg, const u16* __restrict__ Kg, const u16* __restrict__ Vg,
    const float* __restrict__ Dg, const float* __restrict__ Ug,
    u16* __restrict__ Yg, float* __restrict__ Ag, float* __restrict__ Pg)
{
  __shared__ u16 RT_[64 * 72];     // r -> r̃  [i][k]
  __shared__ u16 KT_[64 * 72];     // k -> k̃  [s][k]
  __shared__ u16 KTT_[64 * 72];    // k̃ᵀ [k][s]
  __shared__ u16 V_[64 * 72];      // V [s][j]
  __shared__ u16 VT_[64 * 72];     // Vᵀ [j][s]
  __shared__ char UD_[64 * 68 * 4];// D f32 [i][68], then M u16 [i][72]
  __shared__ float us_[64];
  __shared__ float dg4_[256];
  __shared__ float dg_[64];
  float* D_ = (float*)UD_;
  u16*  M_  = (u16*)UD_;

  const int tid = threadIdx.x;
  const int bh = blockIdx.x >> 5, ch = blockIdx.x & 31;
  const int b = bh >> 4, h = bh & 15, cb = h * 64;
  const long rowb = (long)b * 2048 + ch * 64;

  if (tid < 64) us_[tid] = Ug[cb + tid];

  const int iS = tid >> 2, sg = tid & 3;
  // ---- P0: stage r,k,v(,vT),d
  {
    const long go = (rowb + iS) * 1024 + cb + sg * 16;
    uint4 a0 = *(const uint4*)(Rg + go);
    uint4 a1 = *(const uint4*)(Rg + go + 8);
    u32* rd = (u32*)&RT_[iS * 72 + sg * 16];
    rd[0]=a0.x; rd[1]=a0.y; rd[2]=a0.z; rd[3]=a0.w;
    rd[4]=a1.x; rd[5]=a1.y; rd[6]=a1.z; rd[7]=a1.w;
    a0 = *(const uint4*)(Kg + go); a1 = *(const uint4*)(Kg + go + 8);
    u32* kd = (u32*)&KT_[iS * 72 + sg * 16];
    kd[0]=a0.x; kd[1]=a0.y; kd[2]=a0.z; kd[3]=a0.w;
    kd[4]=a1.x; kd[5]=a1.y; kd[6]=a1.z; kd[7]=a1.w;
    a0 = *(const uint4*)(Vg + go); a1 = *(const uint4*)(Vg + go + 8);
    u32* vd = (u32*)&V_[iS * 72 + sg * 16];
    vd[0]=a0.x; vd[1]=a0.y; vd[2]=a0.z; vd[3]=a0.w;
    vd[4]=a1.x; vd[5]=a1.y; vd[6]=a1.z; vd[7]=a1.w;
    const u32 vw[8] = {a0.x,a0.y,a0.z,a0.w,a1.x,a1.y,a1.z,a1.w};
#pragma unroll
    for (int e = 0; e < 8; e++){
      VT_[(sg*16 + 2*e    ) * 72 + iS] = LOH(vw[e]);
      VT_[(sg*16 + 2*e + 1) * 72 + iS] = HIH(vw[e]);
    }
    const float4* dsrc = (const float4*)(Dg + go);
    float4* dd = (float4*)&D_[iS * 68 + sg * 16];
    dd[0]=dsrc[0]; dd[1]=dsrc[1]; dd[2]=dsrc[2]; dd[3]=dsrc[3];
  }
  __syncthreads();
  // ---- P0b: diag partials with RAW r,k
  {
    const int i = tid & 63, q = tid >> 6;
    const u32* rr = (const u32*)&RT_[i * 72 + q * 16];
    const u32* kr = (const u32*)&KT_[i * 72 + q * 16];
    const float* up = &us_[q * 16];
    float ds = 0.0f;
#pragma unroll
    for (int e = 0; e < 8; e++){
      ds += b2f(LOH(rr[e])) * up[2*e]   * b2f(LOH(kr[e]));
      ds += b2f(HIH(rr[e])) * up[2*e+1] * b2f(HIH(kr[e]));
    }
    dg4_[i * 4 + q] = ds;
  }
  __syncthreads();
  // ---- P0c: prefix decay; RT->r̃, KT->k̃ (and KTT); diag finalize; Pg
  if (tid < 64){
    const int k = tid;
    dg_[k] = dg4_[k*4] + dg4_[k*4+1] + dg4_[k*4+2] + dg4_[k*4+3];
    float pz = 1.0f;
#pragma unroll 4
    for (int i = 0; i < 64; i++){
      const float d = D_[i * 68 + k];
      const int ro = i * 72 + k;
      RT_[ro] = f2b(b2f(RT_[ro]) * pz);
      pz *= d;
      const u16 kb = f2b(b2f(KT_[ro]) * (1.0f / pz));
      KT_[ro] = kb;
      KTT_[k * 72 + i] = kb;
    }
    Pg[((long)bh * 32 + ch) * 64 + k] = pz;
  }
  __syncthreads();
  // ---- writeback r̃ to Rg
  {
    const u32* rr = (const u32*)&RT_[iS * 72 + sg * 16];
    u32* out = (u32*)(Rg + (rowb + iS) * 1024 + cb + sg * 16);
#pragma unroll
    for (int e = 0; e < 8; e++) out[e] = rr[e];
  }
  const int wave = tid >> 6, lane = tid & 63;
  const int wr = wave >> 1, wc = wave & 1;
  const int l16 = lane & 15, kq = lane >> 4;
  // ---- P2: M = r̃·k̃ᵀ, mask s<i, store bf16 to M_
  {
    f32x4 acc[2][2];
#pragma unroll
    for (int a = 0; a < 2; a++)
#pragma unroll
      for (int c = 0; c < 2; c++) acc[a][c] = (f32x4)0.0f;
#pragma unroll
    for (int ks = 0; ks < 2; ks++){
      short8 af[2], bf[2];
#pragma unroll
      for (int mi = 0; mi < 2; mi++) af[mi] = *(const short8*)&RT_[(wr*32 + mi*16 + l16)*72 + ks*32 + kq*8];
#pragma unroll
      for (int ni = 0; ni < 2; ni++) bf[ni] = *(const short8*)&KT_[(wc*32 + ni*16 + l16)*72 + ks*32 + kq*8];
#pragma unroll
      for (int mi = 0; mi < 2; mi++)
#pragma unroll
        for (int ni = 0; ni < 2; ni++)
          acc[mi][ni] = __builtin_amdgcn_mfma_f32_16x16x32_bf16(af[mi], bf[ni], acc[mi][ni], 0, 0, 0);
    }
    __syncthreads();    // D_ dead; M_ union becomes valid
#pragma unroll
    for (int mi = 0; mi < 2; mi++)
#pragma unroll
      for (int ni = 0; ni < 2; ni++)
#pragma unroll
        for (int qq = 0; qq < 4; qq++){
          const int ii = wr*32 + mi*16 + kq*4 + qq;
          const int ss = wc*32 + ni*16 + l16;
          M_[ii * 72 + ss] = f2b(ss < ii ? acc[mi][ni][qq] : 0.0f);
        }
  }
  __syncthreads();
  // ---- P3+P4: Y = M·V + diag·v ; A = k̃ᵀ·V
  {
    f32x4 accY[2][2], accA[2][2];
#pragma unroll
    for (int a = 0; a < 2; a++)
#pragma unroll
      for (int c = 0; c < 2; c++){ accY[a][c] = (f32x4)0.0f; accA[a][c] = (f32x4)0.0f; }
#pragma unroll
    for (int ks = 0; ks < 2; ks++){
      short8 am[2], ak[2], bv[2];
#pragma unroll
      for (int mi = 0; mi < 2; mi++){
        am[mi] = *(const short8*)&M_[(wr*32 + mi*16 + l16)*72 + ks*32 + kq*8];
        ak[mi] = *(const short8*)&KTT_[(wr*32 + mi*16 + l16)*72 + ks*32 + kq*8];
      }
#pragma unroll
      for (int ni = 0; ni < 2; ni++) bv[ni] = *(const short8*)&VT_[(wc*32 + ni*16 + l16)*72 + ks*32 + kq*8];
#pragma unroll
      for (int mi = 0; mi < 2; mi++)
#pragma unroll
        for (int ni = 0; ni < 2; ni++){
          accY[mi][ni] = __builtin_amdgcn_mfma_f32_16x16x32_bf16(am[mi], bv[ni], accY[mi][ni], 0, 0, 0);
          accA[mi][ni] = __builtin_amdgcn_mfma_f32_16x16x32_bf16(ak[mi], bv[ni], accA[mi][ni], 0, 0, 0);
        }
    }
    float* abase = Ag + ((long)bh * 32 + ch) * 4096;
#pragma unroll
    for (int mi = 0; mi < 2; mi++)
#pragma unroll
      for (int qq = 0; qq < 4; qq++){
        const int ii = wr*32 + mi*16 + kq*4 + qq;
        u16* yrow = Yg + (rowb + ii) * 1024 + cb;
        float* arow = abase + ii * 64;
#pragma unroll
        for (int ni = 0; ni < 2; ni++){
          const int jj = wc*32 + ni*16 + l16;
          const float yv = accY[mi][ni][qq] + dg_[ii] * b2f(V_[ii * 72 + jj]);
          yrow[jj] = f2b(yv);
          arow[jj] = accA[mi][ni][qq];
        }
      }
  }
}

// ---------------------------------------------------------------------------
// WKV6 stage 2 — inter-chunk recurrence S_{c+1} = ps_c*(S_c + A_c).
// ---------------------------------------------------------------------------
__global__ __launch_bounds__(256) void wkv_s2(
    const float* __restrict__ Ag, const float* __restrict__ Pg, float* __restrict__ Sg)
{
  const int tid = threadIdx.x;
  const int bh = blockIdx.x >> 2, kq = blockIdx.x & 3;
  const int kk = tid >> 4, jo = tid & 15;
  const int krow = kq * 16 + kk;
  const long base = (long)bh * 32;
  float4 S = make_float4(0.f, 0.f, 0.f, 0.f);
  for (int c = 0; c < 32; c++){
    const long mo = (base + c) * 4096 + krow * 64 + jo * 4;
    *(float4*)(Sg + mo) = S;
    const float4 a = *(const float4*)(Ag + mo);
    const float ps = Pg[(base + c) * 64 + krow];
    S.x = ps * (S.x + a.x); S.y = ps * (S.y + a.y);
    S.z = ps * (S.z + a.z); S.w = ps * (S.w + a.w);
  }
}

// ---------------------------------------------------------------------------
// WKV6 stage 3 — cross term: Yg += rt~ . S_chunkstart (bf16 RMW).
// ---------------------------------------------------------------------------
__global__ __launch_bounds__(256) void wkv_s3(
    const u16* __restrict__ Rtg, const float* __restrict__ Sg, u16* __restrict__ Yg)
{
  __shared__ float Ss[4096];        // [k][j]
  __shared__ u16 RTs[64 * 66];
  const int tid = threadIdx.x;
  const int bh = blockIdx.x >> 5, ch = blockIdx.x & 31;
  if (ch == 0) return;
  const int b = bh >> 4, h = bh & 15, cb = h * 64;
  const long rowb = (long)b * 2048 + ch * 64;

  {
    const float4* sp = (const float4*)(Sg + ((long)bh * 32 + ch) * 4096);
    float4* sd = (float4*)Ss;
#pragma unroll
    for (int e = 0; e < 4; e++) sd[tid + e * 256] = sp[tid + e * 256];
  }
  {
    const int iS = tid >> 2, sg4 = tid & 3;
    const u32* src = (const u32*)(Rtg + (rowb + iS) * 1024 + cb + sg4 * 16);
    u32* dst = (u32*)&RTs[iS * 66 + sg4 * 16];
#pragma unroll
    for (int e = 0; e < 8; e++) dst[e] = src[e];
  }
  __syncthreads();

  const int i_ = tid & 63, q = tid >> 6, jb = q * 16;
  float rt[64];
  {
    const u32* rr = (const u32*)&RTs[i_ * 66];
#pragma unroll
    for (int kk = 0; kk < 32; kk++){
      const u32 u = rr[kk];
      rt[2*kk] = b2f(LOH(u)); rt[2*kk+1] = b2f(HIH(u));
    }
  }
  u16* yo = Yg + (rowb + i_) * 1024 + cb + jb;
  float y[16];
  {
    const u32* yp = (const u32*)yo;
#pragma unroll
    for (int j2 = 0; j2 < 8; j2++){
      const u32 u = yp[j2];
      y[2*j2] = b2f(LOH(u)); y[2*j2+1] = b2f(HIH(u));
    }
  }
#pragma unroll
  for (int k = 0; k < 64; k++){
    const float rk = rt[k];
    const float4* sr = (const float4*)&Ss[k * 64 + jb];
#pragma unroll
    for (int j4 = 0; j4 < 4; j4++){
      const float4 sv = sr[j4];
      y[4*j4+0] += rk*sv.x; y[4*j4+1] += rk*sv.y; y[4*j4+2] += rk*sv.z; y[4*j4+3] += rk*sv.w;
    }
  }
  {
    u32* yp = (u32*)yo;
#pragma unroll
    for (int j2 = 0; j2 < 8; j2++)
      yp[j2] = (u32)f2b(y[2*j2]) | ((u32)f2b(y[2*j2+1]) << 16);
  }
}

// ---------------------------------------------------------------------------
// GroupNorm over each head's 64 channels, then * g   (one block per bt row)
// ---------------------------------------------------------------------------
__global__ __launch_bounds__(256) void gnorm_k(const u16* __restrict__ Y,
    const u16* __restrict__ G, const float* __restrict__ lng,
    const float* __restrict__ lnb, u16* __restrict__ Z)
{
  const long row = blockIdx.x;
  const int tid = threadIdx.x;
  const int hh = tid >> 4, l = tid & 15;
  const int c = hh * 64 + l * 4;
  const u32* yp = (const u32*)(Y + row * 1024 + c);
  const u32 y01 = yp[0], y23 = yp[1];
  const float vv[4] = {b2f(LOH(y01)), b2f(HIH(y01)), b2f(LOH(y23)), b2f(HIH(y23))};
  float s = vv[0] + vv[1] + vv[2] + vv[3];
  float sq = vv[0]*vv[0] + vv[1]*vv[1] + vv[2]*vv[2] + vv[3]*vv[3];
#pragma unroll
  for (int off = 1; off < 16; off <<= 1){ s += __shfl_xor(s, off); sq += __shfl_xor(sq, off); }
  const float mean = s * 0.015625f;
  const float var = sq * 0.015625f - mean * mean;
  const float rstd = rsqrtf(var + 6.4e-4f);   // eps = 1e-5 * 64
  const uint2 gg = *(const uint2*)(G + row * 1024 + c);
  const float4 lg = *(const float4*)(lng + c);
  const float4 lb = *(const float4*)(lnb + c);
  const float lgs[4] = {lg.x, lg.y, lg.z, lg.w};
  const float lbs[4] = {lb.x, lb.y, lb.z, lb.w};
  const u32 gs[2] = {gg.x, gg.y};
  ushort4 o;
  u16* op = (u16*)&o;
#pragma unroll
  for (int e = 0; e < 4; e++){
    const float gv = b2f((e & 1) ? HIH(gs[e >> 1]) : LOH(gs[e >> 1]));
    op[e] = f2b(((vv[e] - mean) * rstd * lgs[e] + lbs[e]) * gv);
  }
  *(ushort4*)(Z + row * 1024 + c) = o;
}

// ---------------------------------------------------------------------------
extern "C" void kernel_launch(void* const* d_in, const int* in_sizes, int n_in,
                              void* d_out, int out_size, void* d_ws, size_t ws_size,
                              hipStream_t stream)
{
  (void)in_sizes; (void)n_in; (void)out_size; (void)ws_size;
  const float* X    = (const float*)d_in[0];
  const float* TMX  = (const float*)d_in[1];
  const float* TMW  = (const float*)d_in[2];
  const float* TMK  = (const float*)d_in[3];
  const float* TMV  = (const float*)d_in[4];
  const float* TMR  = (const float*)d_in[5];
  const float* TMG  = (const float*)d_in[6];
  const float* MW1  = (const float*)d_in[7];
  const float* MW2  = (const float*)d_in[8];
  const float* TD   = (const float*)d_in[9];
  const float* TDW1 = (const float*)d_in[10];
  const float* TDW2 = (const float*)d_in[11];
  const float* U    = (const float*)d_in[12];
  const float* WR   = (const float*)d_in[13];
  const float* WK   = (const float*)d_in[14];
  const float* WV   = (const float*)d_in[15];
  const float* WG   = (const float*)d_in[16];
  const float* WO   = (const float*)d_in[17];
  const float* LNG  = (const float*)d_in[18];
  const float* LNB  = (const float*)d_in[19];

  char* ws = (char*)d_ws;
  const size_t SLOT = 16777216ULL;     // B*T*C bf16 bytes
  u16* S1 = (u16*)(ws + 0 * SLOT);     // XM  -> Rb (-> rt~)
  u16* S2 = (u16*)(ws + 1 * SLOT);     // XW  -> Y (bf16)
  u16* S3 = (u16*)(ws + 2 * SLOT);     // XK
  u16* S4 = (u16*)(ws + 3 * SLOT);     // XV  -> Z
  u16* S5 = (u16*)(ws + 4 * SLOT);     // XR  -> DEC lo
  u16* S6 = (u16*)(ws + 5 * SLOT);     // XG  -> DEC hi
  u16* S7 = (u16*)(ws + 6 * SLOT);     // XBF -> Kb -> Sg lo
  u16* S8 = (u16*)(ws + 7 * SLOT);     // XX  -> Vb -> Sg hi
  u16* S9 = (u16*)(ws + 8 * SLOT);     // Gb
  char* p = ws + 9 * SLOT;
  auto alloc = [&](size_t bytes) -> void* {
    void* q = p; p += (bytes + 255) & ~(size_t)255; return q;
  };
  u16* MIXB = (u16*)alloc(8192ULL * 256 * 2);
  u16* Hb   = (u16*)alloc(8192ULL * 128 * 2);
  u16* W1T  = (u16*)alloc(256ULL * 1024 * 2);
  u16* W2T  = (u16*)alloc(5ULL * 1024 * 32 * 2);
  u16* TW1T = (u16*)alloc(128ULL * 1024 * 2);
  u16* TW2T = (u16*)alloc(1024ULL * 64 * 2);
  u16* WRb  = (u16*)alloc(1048576ULL * 2);
  u16* WKb  = (u16*)alloc(1048576ULL * 2);
  u16* WVb  = (u16*)alloc(1048576ULL * 2);
  u16* WGb  = (u16*)alloc(1048576ULL * 2);
  u16* WOb  = (u16*)alloc(1048576ULL * 2);
  float* Ab = (float*)alloc(33554432ULL);   // [bh][c][64][64] f32
  float* Pg = (float*)alloc(524288ULL);     // [bh][c][64] f32

  u16*   XM = S1; u16* XW = S2; u16* XK = S3; u16* XV = S4; u16* XR = S5; u16* XG = S6;
  u16*   XBF = S7; u16* XX = S8;
  u16*   Rb = S1; u16* Kb = S7; u16* Vb = S8; u16* Gb = S9;
  u16*   Y   = S2;            // bf16 (xw dead after Hb gemm)
  float* DEC = (float*)S5;    // spans S5+S6 (xr,xg dead after rkvg gemm)
  float* Sg  = (float*)S7;    // spans S7+S8 (kb,vb dead after s1)
  u16*   Z   = S4;            // xv dead

  // allow 128KB dynamic LDS for the 256^2 kernels (idempotent, cheap)
  hipFuncSetAttribute(reinterpret_cast<const void*>(gemm256_k<0>),
                      hipFuncAttributeMaxDynamicSharedMemorySize, 131072);
  hipFuncSetAttribute(reinterpret_cast<const void*>(gemm256_k<1>),
                      hipFuncAttributeMaxDynamicSharedMemorySize, 131072);

  // weight casts / transposes (f32 -> bf16, [N][K] K-contiguous)
  Cast5P cp;
  cp.s[0]=WR; cp.s[1]=WK; cp.s[2]=WV; cp.s[3]=WG; cp.s[4]=WO;
  cp.d[0]=WRb; cp.d[1]=WKb; cp.d[2]=WVb; cp.d[3]=WGb; cp.d[4]=WOb;
  cast5_k<<<dim3(1024, 5), 256, 0, stream>>>(cp);
  tpad_k<<<1024, 256, 0, stream>>>(MW1, W1T, 1024, 160, 256LL * 1024);
  tpw2_k<<<640, 256, 0, stream>>>(MW2, W2T);
  tpad_k<<<512, 256, 0, stream>>>(TDW1, TW1T, 1024, 64, 128LL * 1024);
  tpad_k<<<256, 256, 0, stream>>>(TDW2, TW2T, 64, 1024, 1024LL * 64);

  // XM / XBF / XX
  mkxm_k<<<8192, 256, 0, stream>>>(X, TMX, XM, XBF, XX);

  // mix160 = tanh(XM @ maa_w1)        [8192,256(pad)]
  gemm_bt<1><<<dim3(64, 2), 256, 0, stream>>>(XM, 1024, W1T, 1024, MIXB, 256, 1024, nullptr);

  // x{w,k,v,r,g} = x + xx*(tm + mix_f @ maa_w2_f)   — one launch, z-loop inside
  Mix5P mp;
  mp.ex = XBF; mp.exx = XX;
  mp.out[0]=XW; mp.out[1]=XK; mp.out[2]=XV; mp.out[3]=XR; mp.out[4]=XG;
  mp.tm[0]=TMW; mp.tm[1]=TMK; mp.tm[2]=TMV; mp.tm[3]=TMR; mp.tm[4]=TMG;
  gemm_mix5<<<dim3(64, 8), 256, 0, stream>>>(MIXB, W2T, mp);

  // r, k, v, g — fused 256^2 deep-pipelined (Rb over XM; Kb/Vb over XBF/XX)
  G4P gp;
  gp.A[0]=XR; gp.A[1]=XK; gp.A[2]=XV; gp.A[3]=XG;
  gp.B[0]=WRb; gp.B[1]=WKb; gp.B[2]=WVb; gp.B[3]=WGb;
  gp.C[0]=Rb; gp.C[1]=Kb; gp.C[2]=Vb; gp.C[3]=Gb;
  gemm256_k<0><<<dim3(32, 4, 4), 512, 131072, stream>>>(gp, nullptr);

  // h = tanh(xw @ td_w1);  decay = exp(-exp(time_decay + h @ td_w2))
  gemm_bt<1><<<dim3(64, 1), 256, 0, stream>>>(XW, 1024, TW1T, 1024, Hb, 128, 1024, nullptr);
  gemm_bt<3><<<dim3(64, 8), 256, 0, stream>>>(Hb, 128, TW2T, 64, DEC, 1024, 64, TD);

  // WKV6 chunk-parallel scan (Y bf16)
  wkv_s1<<<2048, 256, 0, stream>>>(Rb, Kb, Vb, DEC, U, Y, Ab, Pg);
  wkv_s2<<<256, 256, 0, stream>>>(Ab, Pg, Sg);
  wkv_s3<<<2048, 256, 0, stream>>>(Rb, Sg, Y);

  // GroupNorm(y)*g -> z
  gnorm_k<<<8192, 256, 0, stream>>>(Y, Gb, LNG, LNB, Z);

  // out = z @ Wo^T   (f32 out, 256^2 deep-pipelined)
  G4P go;
  go.A[0]=Z; go.B[0]=WOb; go.C[0]=nullptr;
  gemm256_k<1><<<dim3(32, 4, 1), 512, 131072, stream>>>(go, (float*)d_out);
}

// Round 11
// 335.291 us; speedup vs baseline: 1.1778x; 1.0456x over previous
//
#include <hip/hip_runtime.h>

typedef unsigned int u32;
typedef unsigned short u16;
typedef __attribute__((ext_vector_type(8))) short short8;
typedef __attribute__((ext_vector_type(4))) float f32x4;

__device__ __forceinline__ float b2f(u16 h){ u32 x = ((u32)h) << 16; return __builtin_bit_cast(float, x); }
__device__ __forceinline__ u16 f2b(float f){
  u32 x = __builtin_bit_cast(u32, f);
  x += 0x7fffu + ((x >> 16) & 1u);
  return (u16)(x >> 16);
}
#define LOH(u) ((u16)((u) & 0xffffu))
#define HIH(u) ((u16)((u) >> 16))

__device__ __forceinline__ void gload16(const u16* g, u16* lds){
  __builtin_amdgcn_global_load_lds((const __attribute__((address_space(1))) u32*)g,
                                   (__attribute__((address_space(3))) u32*)lds, 16, 0, 0);
}

// ---------------------------------------------------------------------------
// 128x128-block 4-wave GEMM, TLP-oriented:  C = A[M,K] * B[N,K]^T, K=1024.
// BK=32, 2-buffer 32KB static LDS -> 4 blocks/CU (16 waves/CU), wave tile
// 64x64.  Sync order (R8-proven): STAGE(next) -> vmcnt(4) -> s_barrier ->
// reads/MFMA -> s_barrier (WAR protection for next iter's STAGE).
// 0-conflict XOR swizzle (R8/R9-proven), setprio around MFMA.
// MODE 0: bf16 out via gp.C[z] (z==3 -> SiLU).  MODE 1: f32 out via Cf.
// ---------------------------------------------------------------------------
struct G4P { const u16* A[4]; const u16* B[4]; u16* C[4]; };

template<int MODE>
__global__ __launch_bounds__(256, 4) void gemm128_k(G4P gp, float* __restrict__ Cf)
{
  __shared__ u16 lds[16384];     // 2 bufs x (A 4096 | B 4096) u16 = 32 KB
  const int tid = threadIdx.x;
  const int z = blockIdx.z;
  const u16* __restrict__ A  = gp.A[z];
  const u16* __restrict__ Bw = gp.B[z];
  const int wid = tid >> 6, lane = tid & 63;
  const int wr = wid >> 1, wc = wid & 1;
  const int l16 = lane & 15, kq = lane >> 4;
  const int swr = (l16 >> 1) & 3;       // read-side swizzle key
  const long row0 = (long)blockIdx.x * 128;
  const long col0 = (long)blockIdx.y * 128;

  f32x4 acc[4][4];
#pragma unroll
  for (int i = 0; i < 4; i++)
#pragma unroll
    for (int j = 0; j < 4; j++) acc[i][j] = (f32x4)0.0f;

  // staging: LDS chunk c = tid + it*256; (row, kpos) = (c>>2, c&3);
  // source k-chunk = kpos ^ ((row>>1)&3) = (tid&3) ^ ((tid>>3)&3)
  // (invariant across it: it adds 64 rows -> key shift 32 == 0 mod 4).
  const int srow = tid >> 2;            // 0..63
  const int sk8 = ((tid & 3) ^ ((tid >> 3) & 3)) * 8;
  const u16* Agp = A  + (row0 + srow) * 1024 + sk8;
  const u16* Bgp = Bw + (col0 + srow) * 1024 + sk8;

  auto STAGE = [&](int buf, int kt){
    u16* Ab = lds + buf * 8192;
    u16* Bb = Ab + 4096;
    const int ko = kt * 32;
    gload16(Agp + ko,         Ab + tid * 8);
    gload16(Agp + 65536 + ko, Ab + (tid + 256) * 8);   // +64 rows
    gload16(Bgp + ko,         Bb + tid * 8);
    gload16(Bgp + 65536 + ko, Bb + (tid + 256) * 8);
  };

  STAGE(0, 0);
  const int NT = 32;   // K=1024 / BK=32
  for (int t = 0; t < NT; t++){
    const int cur = t & 1;
    if (t + 1 < NT){
      STAGE(cur ^ 1, t + 1);             // buf cur^1: reads ended at prev end-of-iter barrier
      asm volatile("s_waitcnt vmcnt(4)" ::: "memory");   // own tile-t loads landed
    } else {
      asm volatile("s_waitcnt vmcnt(0)" ::: "memory");
    }
    __builtin_amdgcn_sched_barrier(0);
    __builtin_amdgcn_s_barrier();        // promotes per-wave vmcnt to block-wide guarantee
    __builtin_amdgcn_sched_barrier(0);
    const u16* Ab = lds + cur * 8192;
    const u16* Bb = Ab + 4096;
    short8 afr[4], bfr[4];
#pragma unroll
    for (int ni = 0; ni < 4; ni++)
      bfr[ni] = *(const short8*)&Bb[(wc*64 + ni*16 + l16)*32 + (kq ^ swr)*8];
#pragma unroll
    for (int mi = 0; mi < 4; mi++)
      afr[mi] = *(const short8*)&Ab[(wr*64 + mi*16 + l16)*32 + (kq ^ swr)*8];
    __builtin_amdgcn_s_setprio(1);
#pragma unroll
    for (int mi = 0; mi < 4; mi++)
#pragma unroll
      for (int ni = 0; ni < 4; ni++)
        acc[mi][ni] = __builtin_amdgcn_mfma_f32_16x16x32_bf16(afr[mi], bfr[ni], acc[mi][ni], 0, 0, 0);
    __builtin_amdgcn_s_setprio(0);
    __builtin_amdgcn_s_barrier();        // all waves done reading buf cur -> next iter may stage it
  }

  const bool SILU = (MODE == 0) && (z == 3);
#pragma unroll
  for (int mi = 0; mi < 4; mi++){
#pragma unroll
    for (int qq = 0; qq < 4; qq++){
      const long r = row0 + wr*64 + mi*16 + kq*4 + qq;
      if (MODE == 0){
        u16* crow = gp.C[z] + r * 1024 + col0 + wc*64 + l16;
#pragma unroll
        for (int ni = 0; ni < 4; ni++){
          float v = acc[mi][ni][qq];
          if (SILU) v = v / (1.0f + expf(-v));
          crow[ni * 16] = f2b(v);
        }
      } else {
        float* crow = Cf + r * 1024 + col0 + wc*64 + l16;
#pragma unroll
        for (int ni = 0; ni < 4; ni++)
          crow[ni * 16] = acc[mi][ni][qq];
      }
    }
  }
}

// ---------------------------------------------------------------------------
// Generic MFMA GEMM: C[M,N] = A[M,K] * B[N,K]^T   (A,B bf16 K-contiguous)
// 128x128 tile, BK=32, 256 threads (4 waves 2x2), 16x16x32 bf16 MFMA.
// EPI: 0 bf16, 1 tanh bf16, 3 decay f32 (e_vec), 4 silu bf16, 5 plain f32
// ---------------------------------------------------------------------------
template<int EPI>
__global__ __launch_bounds__(256) void gemm_bt(
    const u16* __restrict__ A, int lda,
    const u16* __restrict__ B, int ldb,
    void* __restrict__ Cv, int ldc, int K,
    const float* __restrict__ e_vec)
{
  __shared__ u16 As[4096];
  __shared__ u16 Bs[4096];
  const int tid = threadIdx.x;
  const int wave = tid >> 6, lane = tid & 63;
  const int wr = wave >> 1, wc = wave & 1;
  const int l16 = lane & 15, kq = lane >> 4;
  const long row0 = (long)blockIdx.x * 128;
  const long col0 = (long)blockIdx.y * 128;

  f32x4 acc[4][4];
#pragma unroll
  for (int i = 0; i < 4; i++)
#pragma unroll
    for (int j = 0; j < 4; j++) acc[i][j] = (f32x4)0.0f;

  const int c0 = tid, c1 = tid + 256;
  const u16* Ag0 = A + (row0 + (c0 >> 2)) * (long)lda + (c0 & 3) * 8;
  const u16* Ag1 = A + (row0 + (c1 >> 2)) * (long)lda + (c1 & 3) * 8;
  const u16* Bg0 = B + (col0 + (c0 >> 2)) * (long)ldb + (c0 & 3) * 8;
  const u16* Bg1 = B + (col0 + (c1 >> 2)) * (long)ldb + (c1 & 3) * 8;
  u16* Al0 = &As[c0 * 8]; u16* Al1 = &As[c1 * 8];
  u16* Bl0 = &Bs[c0 * 8]; u16* Bl1 = &Bs[c1 * 8];

  for (int kk = 0; kk < K; kk += 32){
    __syncthreads();
    gload16(Ag0 + kk, Al0);
    gload16(Ag1 + kk, Al1);
    gload16(Bg0 + kk, Bl0);
    gload16(Bg1 + kk, Bl1);
    __syncthreads();
    short8 af[4], bfr[4];
#pragma unroll
    for (int mi = 0; mi < 4; mi++) af[mi]  = *(const short8*)&As[(wr*64 + mi*16 + l16)*32 + kq*8];
#pragma unroll
    for (int ni = 0; ni < 4; ni++) bfr[ni] = *(const short8*)&Bs[(wc*64 + ni*16 + l16)*32 + kq*8];
#pragma unroll
    for (int mi = 0; mi < 4; mi++)
#pragma unroll
      for (int ni = 0; ni < 4; ni++)
        acc[mi][ni] = __builtin_amdgcn_mfma_f32_16x16x32_bf16(af[mi], bfr[ni], acc[mi][ni], 0, 0, 0);
  }

#pragma unroll
  for (int mi = 0; mi < 4; mi++){
#pragma unroll
    for (int qq = 0; qq < 4; qq++){
      const long r = row0 + wr*64 + mi*16 + kq*4 + qq;   // C/D: row=(lane>>4)*4+reg
#pragma unroll
      for (int ni = 0; ni < 4; ni++){
        const long c = col0 + wc*64 + ni*16 + l16;        //      col=lane&15
        const float v = acc[mi][ni][qq];
        if (EPI == 0){
          ((u16*)Cv)[r * ldc + c] = f2b(v);
        } else if (EPI == 1){
          ((u16*)Cv)[r * ldc + c] = f2b(tanhf(v));
        } else if (EPI == 3){
          const float w = v + e_vec[c];
          ((float*)Cv)[r * ldc + c] = expf(-expf(w));
        } else if (EPI == 4){
          ((u16*)Cv)[r * ldc + c] = f2b(v / (1.0f + expf(-v)));
        } else {
          ((float*)Cv)[r * ldc + c] = v;
        }
      }
    }
  }
}

// ---------------------------------------------------------------------------
// Fused 5-way token-mix GEMM, z-loop INSIDE: one block computes the 128x128
// tile for all 5 f's.  C_f = bf16( x + xx * (tm_f + MIXB_f @ W2T_f^T) ).
// A-tile [128][160] staged once (2560 16B chunks); ex/exx hoisted to regs.
// ---------------------------------------------------------------------------
struct Mix5P { const u16* ex; const u16* exx; u16* out[5]; const float* tm[5]; };

__global__ __launch_bounds__(256) void gemm_mix5(
    const u16* __restrict__ Am, const u16* __restrict__ W2T, Mix5P mp)
{
  __shared__ u16 As[128 * 160];   // 40 KB, stride 160
  __shared__ u16 Bs[128 * 32];    // 8 KB
  const int tid = threadIdx.x;
  const int wave = tid >> 6, lane = tid & 63;
  const int wr = wave >> 1, wc = wave & 1;
  const int l16 = lane & 15, kq = lane >> 4;
  const long row0 = (long)blockIdx.x * 128;
  const long col0 = (long)blockIdx.y * 128;

  // stage A-tile [128][160]: 160 u16/row = 20 chunks/row, 2560 chunks total.
#pragma unroll
  for (int it = 0; it < 10; it++){
    const int c = tid + it * 256;
    const int r = c / 20, c8 = c - r * 20;
    gload16(Am + (row0 + r) * 256 + c8 * 8, &As[c * 8]);
  }

  // hoisted ex/exx loads: 64 positions, packed (ex lo | exx hi)
  u32 pxx[64];
#pragma unroll
  for (int mi = 0; mi < 4; mi++)
#pragma unroll
    for (int qq = 0; qq < 4; qq++){
      const long r = row0 + wr*64 + mi*16 + kq*4 + qq;
#pragma unroll
      for (int ni = 0; ni < 4; ni++){
        const long c = col0 + wc*64 + ni*16 + l16;
        const u16 a = mp.ex[r * 1024 + c];
        const u16 b = mp.exx[r * 1024 + c];
        pxx[mi*16 + qq*4 + ni] = (u32)a | ((u32)b << 16);
      }
    }

  for (int z = 0; z < 5; z++){
    __syncthreads();
    const u16* B = W2T + z * 32768;
#pragma unroll
    for (int it = 0; it < 2; it++){
      const int c = tid + it * 256;
      gload16(B + (col0 + (c >> 2)) * 32 + (c & 3) * 8, &Bs[c * 8]);
    }
    __syncthreads();
    short8 af[4], bfr[4];
#pragma unroll
    for (int mi = 0; mi < 4; mi++) af[mi]  = *(const short8*)&As[(wr*64 + mi*16 + l16)*160 + z*32 + kq*8];
#pragma unroll
    for (int ni = 0; ni < 4; ni++) bfr[ni] = *(const short8*)&Bs[(wc*64 + ni*16 + l16)*32 + kq*8];
    f32x4 acc[4][4];
#pragma unroll
    for (int i = 0; i < 4; i++)
#pragma unroll
      for (int j = 0; j < 4; j++) acc[i][j] = (f32x4)0.0f;
#pragma unroll
    for (int mi = 0; mi < 4; mi++)
#pragma unroll
      for (int ni = 0; ni < 4; ni++)
        acc[mi][ni] = __builtin_amdgcn_mfma_f32_16x16x32_bf16(af[mi], bfr[ni], acc[mi][ni], 0, 0, 0);

    const float* tm = mp.tm[z];
    float tmv[4];
#pragma unroll
    for (int ni = 0; ni < 4; ni++) tmv[ni] = tm[col0 + wc*64 + ni*16 + l16];
    u16* C = mp.out[z];
#pragma unroll
    for (int mi = 0; mi < 4; mi++){
#pragma unroll
      for (int qq = 0; qq < 4; qq++){
        const long r = row0 + wr*64 + mi*16 + kq*4 + qq;
        u16* crow = C + r * 1024 + col0 + wc*64 + l16;
#pragma unroll
        for (int ni = 0; ni < 4; ni++){
          const u32 pk = pxx[mi*16 + qq*4 + ni];
          const float xc = b2f(LOH(pk));
          const float xx = b2f(HIH(pk));
          crow[ni * 16] = f2b(xc + xx * (tmv[ni] + acc[mi][ni][qq]));
        }
      }
    }
  }
}

// ---------------------------------------------------------------------------
// XM = bf16(x + (xp-x)*tmx);  XBF = bf16(x);  XX = bf16(xp - x)
// ---------------------------------------------------------------------------
__global__ __launch_bounds__(256) void mkxm_k(const float* __restrict__ X,
    const float* __restrict__ tmx, u16* __restrict__ XM,
    u16* __restrict__ XBF, u16* __restrict__ XXo)
{
  const long idx = (long)blockIdx.x * 256 + threadIdx.x;
  const long m = idx >> 8;
  const int c4 = (int)(idx & 255) * 4;
  const float4 x = *(const float4*)(X + m * 1024 + c4);
  float4 p = make_float4(0.f, 0.f, 0.f, 0.f);
  if ((m & 2047) != 0) p = *(const float4*)(X + (m - 1) * 1024 + c4);
  const float4 t = *(const float4*)(tmx + c4);
  ushort4 o;
  o.x = f2b(x.x + (p.x - x.x) * t.x);
  o.y = f2b(x.y + (p.y - x.y) * t.y);
  o.z = f2b(x.z + (p.z - x.z) * t.z);
  o.w = f2b(x.w + (p.w - x.w) * t.w);
  *(ushort4*)(XM + m * 1024 + c4) = o;
  ushort4 ob; ob.x = f2b(x.x); ob.y = f2b(x.y); ob.z = f2b(x.z); ob.w = f2b(x.w);
  *(ushort4*)(XBF + m * 1024 + c4) = ob;
  ushort4 ox; ox.x = f2b(p.x - x.x); ox.y = f2b(p.y - x.y); ox.z = f2b(p.z - x.z); ox.w = f2b(p.w - x.w);
  *(ushort4*)(XXo + m * 1024 + c4) = ox;
}

// ---------------------------------------------------------------------------
// 5 weight casts in one launch (blockIdx.y = which)
// ---------------------------------------------------------------------------
struct Cast5P { const float* s[5]; u16* d[5]; };
__global__ __launch_bounds__(256) void cast5_k(Cast5P cp)
{
  const int w = blockIdx.y;
  const long i = (long)blockIdx.x * 256 + threadIdx.x;
  const float4 v = ((const float4*)cp.s[w])[i];
  ushort4 o; o.x = f2b(v.x); o.y = f2b(v.y); o.z = f2b(v.z); o.w = f2b(v.w);
  ((ushort4*)cp.d[w])[i] = o;
}

// ---------------------------------------------------------------------------
// Fused small-weight prep (one launch, blockIdx.y = which):
//  y=0: MW1 [1024][160] -> W1T [256][1024] (pad to 256 cols)
//  y=1: MW2 [5][32][1024] -> W2T [5][1024][32]
//  y=2: TDW1 [1024][64] -> TW1T [128][1024] (pad)
//  y=3: TDW2 [64][1024] -> TW2T [1024][64]
// ---------------------------------------------------------------------------
struct PrepP { const float* mw1; const float* mw2; const float* tdw1; const float* tdw2;
               u16* w1t; u16* w2t; u16* tw1t; u16* tw2t; };
__global__ __launch_bounds__(256) void prep_k(PrepP pp)
{
  const int y = blockIdx.y;
  const long idx = (long)blockIdx.x * 256 + threadIdx.x;
  if (y == 0){
    if (idx >= 262144) return;
    const int k = (int)(idx & 1023);       // idx = n*1024 + k
    const int n = (int)(idx >> 10);
    pp.w1t[idx] = (n < 160) ? f2b(pp.mw1[(long)k * 160 + n]) : (u16)0;
  } else if (y == 1){
    if (idx >= 163840) return;
    const int k = (int)(idx & 31);
    const int col = (int)(idx >> 5) & 1023;
    const int f = (int)(idx >> 15);
    pp.w2t[idx] = f2b(pp.mw2[f * 32768 + k * 1024 + col]);
  } else if (y == 2){
    if (idx >= 131072) return;
    const int k = (int)(idx & 1023);
    const int n = (int)(idx >> 10);
    pp.tw1t[idx] = (n < 64) ? f2b(pp.tdw1[(long)k * 64 + n]) : (u16)0;
  } else {
    if (idx >= 65536) return;
    const int k = (int)(idx & 63);
    const int n = (int)(idx >> 6);
    pp.tw2t[idx] = f2b(pp.tdw2[(long)k * 1024 + n]);
  }
}

// ---------------------------------------------------------------------------
// WKV6 stage 1 (MFMA). Block per (b,h,chunk).
//  M = r̃·k̃ᵀ (masked s<i), Y = M·V + diag·v (bf16 out), A = k̃ᵀ·V, r̃ -> Rg, Pg.
// ---------------------------------------------------------------------------
__global__ __launch_bounds__(256) void wkv_s1(
    u16* __restrict__ Rg, const u16* __restrict__ Kg, const u16* __restrict__ Vg,
    const float* __restrict__ Dg, const float* __restrict__ Ug,
    u16* __restrict__ Yg, float* __restrict__ Ag, float* __restrict__ Pg)
{
  __shared__ u16 RT_[64 * 72];     // r -> r̃  [i][k]
  __shared__ u16 KT_[64 * 72];     // k -> k̃  [s][k]
  __shared__ u16 KTT_[64 * 72];    // k̃ᵀ [k][s]
  __shared__ u16 V_[64 * 72];      // V [s][j]
  __shared__ u16 VT_[64 * 72];     // Vᵀ [j][s]
  __shared__ char UD_[64 * 68 * 4];// D f32 [i][68], then M u16 [i][72]
  __shared__ float us_[64];
  __shared__ float dg4_[256];
  __shared__ float dg_[64];
  float* D_ = (float*)UD_;
  u16*  M_  = (u16*)UD_;

  const int tid = threadIdx.x;
  const int bh = blockIdx.x >> 5, ch = blockIdx.x & 31;
  const int b = bh >> 4, h = bh & 15, cb = h * 64;
  const long rowb = (long)b * 2048 + ch * 64;

  if (tid < 64) us_[tid] = Ug[cb + tid];

  const int iS = tid >> 2, sg = tid & 3;
  // ---- P0: stage r,k,v(,vT),d
  {
    const long go = (rowb + iS) * 1024 + cb + sg * 16;
    uint4 a0 = *(const uint4*)(Rg + go);
    uint4 a1 = *(const uint4*)(Rg + go + 8);
    u32* rd = (u32*)&RT_[iS * 72 + sg * 16];
    rd[0]=a0.x; rd[1]=a0.y; rd[2]=a0.z; rd[3]=a0.w;
    rd[4]=a1.x; rd[5]=a1.y; rd[6]=a1.z; rd[7]=a1.w;
    a0 = *(const uint4*)(Kg + go); a1 = *(const uint4*)(Kg + go + 8);
    u32* kd = (u32*)&KT_[iS * 72 + sg * 16];
    kd[0]=a0.x; kd[1]=a0.y; kd[2]=a0.z; kd[3]=a0.w;
    kd[4]=a1.x; kd[5]=a1.y; kd[6]=a1.z; kd[7]=a1.w;
    a0 = *(const uint4*)(Vg + go); a1 = *(const uint4*)(Vg + go + 8);
    u32* vd = (u32*)&V_[iS * 72 + sg * 16];
    vd[0]=a0.x; vd[1]=a0.y; vd[2]=a0.z; vd[3]=a0.w;
    vd[4]=a1.x; vd[5]=a1.y; vd[6]=a1.z; vd[7]=a1.w;
    const u32 vw[8] = {a0.x,a0.y,a0.z,a0.w,a1.x,a1.y,a1.z,a1.w};
#pragma unroll
    for (int e = 0; e < 8; e++){
      VT_[(sg*16 + 2*e    ) * 72 + iS] = LOH(vw[e]);
      VT_[(sg*16 + 2*e + 1) * 72 + iS] = HIH(vw[e]);
    }
    const float4* dsrc = (const float4*)(Dg + go);
    float4* dd = (float4*)&D_[iS * 68 + sg * 16];
    dd[0]=dsrc[0]; dd[1]=dsrc[1]; dd[2]=dsrc[2]; dd[3]=dsrc[3];
  }
  __syncthreads();
  // ---- P0b: diag partials with RAW r,k
  {
    const int i = tid & 63, q = tid >> 6;
    const u32* rr = (const u32*)&RT_[i * 72 + q * 16];
    const u32* kr = (const u32*)&KT_[i * 72 + q * 16];
    const float* up = &us_[q * 16];
    float ds = 0.0f;
#pragma unroll
    for (int e = 0; e < 8; e++){
      ds += b2f(LOH(rr[e])) * up[2*e]   * b2f(LOH(kr[e]));
      ds += b2f(HIH(rr[e])) * up[2*e+1] * b2f(HIH(kr[e]));
    }
    dg4_[i * 4 + q] = ds;
  }
  __syncthreads();
  // ---- P0c: prefix decay; RT->r̃, KT->k̃ (and KTT); diag finalize; Pg
  if (tid < 64){
    const int k = tid;
    dg_[k] = dg4_[k*4] + dg4_[k*4+1] + dg4_[k*4+2] + dg4_[k*4+3];
    float pz = 1.0f;
#pragma unroll 4
    for (int i = 0; i < 64; i++){
      const float d = D_[i * 68 + k];
      const int ro = i * 72 + k;
      RT_[ro] = f2b(b2f(RT_[ro]) * pz);
      pz *= d;
      const u16 kb = f2b(b2f(KT_[ro]) * (1.0f / pz));
      KT_[ro] = kb;
      KTT_[k * 72 + i] = kb;
    }
    Pg[((long)bh * 32 + ch) * 64 + k] = pz;
  }
  __syncthreads();
  // ---- writeback r̃ to Rg
  {
    const u32* rr = (const u32*)&RT_[iS * 72 + sg * 16];
    u32* out = (u32*)(Rg + (rowb + iS) * 1024 + cb + sg * 16);
#pragma unroll
    for (int e = 0; e < 8; e++) out[e] = rr[e];
  }
  const int wave = tid >> 6, lane = tid & 63;
  const int wr = wave >> 1, wc = wave & 1;
  const int l16 = lane & 15, kq = lane >> 4;
  // ---- P2: M = r̃·k̃ᵀ, mask s<i, store bf16 to M_
  {
    f32x4 acc[2][2];
#pragma unroll
    for (int a = 0; a < 2; a++)
#pragma unroll
      for (int c = 0; c < 2; c++) acc[a][c] = (f32x4)0.0f;
#pragma unroll
    for (int ks = 0; ks < 2; ks++){
      short8 af[2], bf[2];
#pragma unroll
      for (int mi = 0; mi < 2; mi++) af[mi] = *(const short8*)&RT_[(wr*32 + mi*16 + l16)*72 + ks*32 + kq*8];
#pragma unroll
      for (int ni = 0; ni < 2; ni++) bf[ni] = *(const short8*)&KT_[(wc*32 + ni*16 + l16)*72 + ks*32 + kq*8];
#pragma unroll
      for (int mi = 0; mi < 2; mi++)
#pragma unroll
        for (int ni = 0; ni < 2; ni++)
          acc[mi][ni] = __builtin_amdgcn_mfma_f32_16x16x32_bf16(af[mi], bf[ni], acc[mi][ni], 0, 0, 0);
    }
    __syncthreads();    // D_ dead; M_ union becomes valid
#pragma unroll
    for (int mi = 0; mi < 2; mi++)
#pragma unroll
      for (int ni = 0; ni < 2; ni++)
#pragma unroll
        for (int qq = 0; qq < 4; qq++){
          const int ii = wr*32 + mi*16 + kq*4 + qq;
          const int ss = wc*32 + ni*16 + l16;
          M_[ii * 72 + ss] = f2b(ss < ii ? acc[mi][ni][qq] : 0.0f);
        }
  }
  __syncthreads();
  // ---- P3+P4: Y = M·V + diag·v ; A = k̃ᵀ·V
  {
    f32x4 accY[2][2], accA[2][2];
#pragma unroll
    for (int a = 0; a < 2; a++)
#pragma unroll
      for (int c = 0; c < 2; c++){ accY[a][c] = (f32x4)0.0f; accA[a][c] = (f32x4)0.0f; }
#pragma unroll
    for (int ks = 0; ks < 2; ks++){
      short8 am[2], ak[2], bv[2];
#pragma unroll
      for (int mi = 0; mi < 2; mi++){
        am[mi] = *(const short8*)&M_[(wr*32 + mi*16 + l16)*72 + ks*32 + kq*8];
        ak[mi] = *(const short8*)&KTT_[(wr*32 + mi*16 + l16)*72 + ks*32 + kq*8];
      }
#pragma unroll
      for (int ni = 0; ni < 2; ni++) bv[ni] = *(const short8*)&VT_[(wc*32 + ni*16 + l16)*72 + ks*32 + kq*8];
#pragma unroll
      for (int mi = 0; mi < 2; mi++)
#pragma unroll
        for (int ni = 0; ni < 2; ni++){
          accY[mi][ni] = __builtin_amdgcn_mfma_f32_16x16x32_bf16(am[mi], bv[ni], accY[mi][ni], 0, 0, 0);
          accA[mi][ni] = __builtin_amdgcn_mfma_f32_16x16x32_bf16(ak[mi], bv[ni], accA[mi][ni], 0, 0, 0);
        }
    }
    float* abase = Ag + ((long)bh * 32 + ch) * 4096;
#pragma unroll
    for (int mi = 0; mi < 2; mi++)
#pragma unroll
      for (int qq = 0; qq < 4; qq++){
        const int ii = wr*32 + mi*16 + kq*4 + qq;
        u16* yrow = Yg + (rowb + ii) * 1024 + cb;
        float* arow = abase + ii * 64;
#pragma unroll
        for (int ni = 0; ni < 2; ni++){
          const int jj = wc*32 + ni*16 + l16;
          const float yv = accY[mi][ni][qq] + dg_[ii] * b2f(V_[ii * 72 + jj]);
          yrow[jj] = f2b(yv);
          arow[jj] = accA[mi][ni][qq];
        }
      }
  }
}

// ---------------------------------------------------------------------------
// WKV6 stage 2 — inter-chunk recurrence S_{c+1} = ps_c*(S_c + A_c).
// ---------------------------------------------------------------------------
__global__ __launch_bounds__(256) void wkv_s2(
    const float* __restrict__ Ag, const float* __restrict__ Pg, float* __restrict__ Sg)
{
  const int tid = threadIdx.x;
  const int bh = blockIdx.x >> 2, kq = blockIdx.x & 3;
  const int kk = tid >> 4, jo = tid & 15;
  const int krow = kq * 16 + kk;
  const long base = (long)bh * 32;
  float4 S = make_float4(0.f, 0.f, 0.f, 0.f);
  for (int c = 0; c < 32; c++){
    const long mo = (base + c) * 4096 + krow * 64 + jo * 4;
    *(float4*)(Sg + mo) = S;
    const float4 a = *(const float4*)(Ag + mo);
    const float ps = Pg[(base + c) * 64 + krow];
    S.x = ps * (S.x + a.x); S.y = ps * (S.y + a.y);
    S.z = ps * (S.z + a.z); S.w = ps * (S.w + a.w);
  }
}

// ---------------------------------------------------------------------------
// WKV6 stage 3 — cross term: Yg += rt~ . S_chunkstart (bf16 RMW).
// ---------------------------------------------------------------------------
__global__ __launch_bounds__(256) void wkv_s3(
    const u16* __restrict__ Rtg, const float* __restrict__ Sg, u16* __restrict__ Yg)
{
  __shared__ float Ss[4096];        // [k][j]
  __shared__ u16 RTs[64 * 66];
  const int tid = threadIdx.x;
  const int bh = blockIdx.x >> 5, ch = blockIdx.x & 31;
  if (ch == 0) return;
  const int b = bh >> 4, h = bh & 15, cb = h * 64;
  const long rowb = (long)b * 2048 + ch * 64;

  {
    const float4* sp = (const float4*)(Sg + ((long)bh * 32 + ch) * 4096);
    float4* sd = (float4*)Ss;
#pragma unroll
    for (int e = 0; e < 4; e++) sd[tid + e * 256] = sp[tid + e * 256];
  }
  {
    const int iS = tid >> 2, sg4 = tid & 3;
    const u32* src = (const u32*)(Rtg + (rowb + iS) * 1024 + cb + sg4 * 16);
    u32* dst = (u32*)&RTs[iS * 66 + sg4 * 16];
#pragma unroll
    for (int e = 0; e < 8; e++) dst[e] = src[e];
  }
  __syncthreads();

  const int i_ = tid & 63, q = tid >> 6, jb = q * 16;
  float rt[64];
  {
    const u32* rr = (const u32*)&RTs[i_ * 66];
#pragma unroll
    for (int kk = 0; kk < 32; kk++){
      const u32 u = rr[kk];
      rt[2*kk] = b2f(LOH(u)); rt[2*kk+1] = b2f(HIH(u));
    }
  }
  u16* yo = Yg + (rowb + i_) * 1024 + cb + jb;
  float y[16];
  {
    const u32* yp = (const u32*)yo;
#pragma unroll
    for (int j2 = 0; j2 < 8; j2++){
      const u32 u = yp[j2];
      y[2*j2] = b2f(LOH(u)); y[2*j2+1] = b2f(HIH(u));
    }
  }
#pragma unroll
  for (int k = 0; k < 64; k++){
    const float rk = rt[k];
    const float4* sr = (const float4*)&Ss[k * 64 + jb];
#pragma unroll
    for (int j4 = 0; j4 < 4; j4++){
      const float4 sv = sr[j4];
      y[4*j4+0] += rk*sv.x; y[4*j4+1] += rk*sv.y; y[4*j4+2] += rk*sv.z; y[4*j4+3] += rk*sv.w;
    }
  }
  {
    u32* yp = (u32*)yo;
#pragma unroll
    for (int j2 = 0; j2 < 8; j2++)
      yp[j2] = (u32)f2b(y[2*j2]) | ((u32)f2b(y[2*j2+1]) << 16);
  }
}

// ---------------------------------------------------------------------------
// GroupNorm over each head's 64 channels, then * g   (one block per bt row)
// ---------------------------------------------------------------------------
__global__ __launch_bounds__(256) void gnorm_k(const u16* __restrict__ Y,
    const u16* __restrict__ G, const float* __restrict__ lng,
    const float* __restrict__ lnb, u16* __restrict__ Z)
{
  const long row = blockIdx.x;
  const int tid = threadIdx.x;
  const int hh = tid >> 4, l = tid & 15;
  const int c = hh * 64 + l * 4;
  const u32* yp = (const u32*)(Y + row * 1024 + c);
  const u32 y01 = yp[0], y23 = yp[1];
  const float vv[4] = {b2f(LOH(y01)), b2f(HIH(y01)), b2f(LOH(y23)), b2f(HIH(y23))};
  float s = vv[0] + vv[1] + vv[2] + vv[3];
  float sq = vv[0]*vv[0] + vv[1]*vv[1] + vv[2]*vv[2] + vv[3]*vv[3];
#pragma unroll
  for (int off = 1; off < 16; off <<= 1){ s += __shfl_xor(s, off); sq += __shfl_xor(sq, off); }
  const float mean = s * 0.015625f;
  const float var = sq * 0.015625f - mean * mean;
  const float rstd = rsqrtf(var + 6.4e-4f);   // eps = 1e-5 * 64
  const uint2 gg = *(const uint2*)(G + row * 1024 + c);
  const float4 lg = *(const float4*)(lng + c);
  const float4 lb = *(const float4*)(lnb + c);
  const float lgs[4] = {lg.x, lg.y, lg.z, lg.w};
  const float lbs[4] = {lb.x, lb.y, lb.z, lb.w};
  const u32 gs[2] = {gg.x, gg.y};
  ushort4 o;
  u16* op = (u16*)&o;
#pragma unroll
  for (int e = 0; e < 4; e++){
    const float gv = b2f((e & 1) ? HIH(gs[e >> 1]) : LOH(gs[e >> 1]));
    op[e] = f2b(((vv[e] - mean) * rstd * lgs[e] + lbs[e]) * gv);
  }
  *(ushort4*)(Z + row * 1024 + c) = o;
}

// ---------------------------------------------------------------------------
extern "C" void kernel_launch(void* const* d_in, const int* in_sizes, int n_in,
                              void* d_out, int out_size, void* d_ws, size_t ws_size,
                              hipStream_t stream)
{
  (void)in_sizes; (void)n_in; (void)out_size; (void)ws_size;
  const float* X    = (const float*)d_in[0];
  const float* TMX  = (const float*)d_in[1];
  const float* TMW  = (const float*)d_in[2];
  const float* TMK  = (const float*)d_in[3];
  const float* TMV  = (const float*)d_in[4];
  const float* TMR  = (const float*)d_in[5];
  const float* TMG  = (const float*)d_in[6];
  const float* MW1  = (const float*)d_in[7];
  const float* MW2  = (const float*)d_in[8];
  const float* TD   = (const float*)d_in[9];
  const float* TDW1 = (const float*)d_in[10];
  const float* TDW2 = (const float*)d_in[11];
  const float* U    = (const float*)d_in[12];
  const float* WR   = (const float*)d_in[13];
  const float* WK   = (const float*)d_in[14];
  const float* WV   = (const float*)d_in[15];
  const float* WG   = (const float*)d_in[16];
  const float* WO   = (const float*)d_in[17];
  const float* LNG  = (const float*)d_in[18];
  const float* LNB  = (const float*)d_in[19];

  char* ws = (char*)d_ws;
  const size_t SLOT = 16777216ULL;     // B*T*C bf16 bytes
  u16* S1 = (u16*)(ws + 0 * SLOT);     // XM  -> Rb (-> rt~)
  u16* S2 = (u16*)(ws + 1 * SLOT);     // XW  -> Y (bf16)
  u16* S3 = (u16*)(ws + 2 * SLOT);     // XK
  u16* S4 = (u16*)(ws + 3 * SLOT);     // XV  -> Z
  u16* S5 = (u16*)(ws + 4 * SLOT);     // XR  -> DEC lo
  u16* S6 = (u16*)(ws + 5 * SLOT);     // XG  -> DEC hi
  u16* S7 = (u16*)(ws + 6 * SLOT);     // XBF -> Kb -> Sg lo
  u16* S8 = (u16*)(ws + 7 * SLOT);     // XX  -> Vb -> Sg hi
  u16* S9 = (u16*)(ws + 8 * SLOT);     // Gb
  char* p = ws + 9 * SLOT;
  auto alloc = [&](size_t bytes) -> void* {
    void* q = p; p += (bytes + 255) & ~(size_t)255; return q;
  };
  u16* MIXB = (u16*)alloc(8192ULL * 256 * 2);
  u16* Hb   = (u16*)alloc(8192ULL * 128 * 2);
  u16* W1T  = (u16*)alloc(256ULL * 1024 * 2);
  u16* W2T  = (u16*)alloc(5ULL * 1024 * 32 * 2);
  u16* TW1T = (u16*)alloc(128ULL * 1024 * 2);
  u16* TW2T = (u16*)alloc(1024ULL * 64 * 2);
  u16* WRb  = (u16*)alloc(1048576ULL * 2);
  u16* WKb  = (u16*)alloc(1048576ULL * 2);
  u16* WVb  = (u16*)alloc(1048576ULL * 2);
  u16* WGb  = (u16*)alloc(1048576ULL * 2);
  u16* WOb  = (u16*)alloc(1048576ULL * 2);
  float* Ab = (float*)alloc(33554432ULL);   // [bh][c][64][64] f32
  float* Pg = (float*)alloc(524288ULL);     // [bh][c][64] f32

  u16*   XM = S1; u16* XW = S2; u16* XK = S3; u16* XV = S4; u16* XR = S5; u16* XG = S6;
  u16*   XBF = S7; u16* XX = S8;
  u16*   Rb = S1; u16* Kb = S7; u16* Vb = S8; u16* Gb = S9;
  u16*   Y   = S2;            // bf16 (xw dead after Hb gemm)
  float* DEC = (float*)S5;    // spans S5+S6 (xr,xg dead after rkvg gemm)
  float* Sg  = (float*)S7;    // spans S7+S8 (kb,vb dead after s1)
  u16*   Z   = S4;            // xv dead

  // weight casts (1 launch) + small-weight transposes (1 launch)
  Cast5P cp;
  cp.s[0]=WR; cp.s[1]=WK; cp.s[2]=WV; cp.s[3]=WG; cp.s[4]=WO;
  cp.d[0]=WRb; cp.d[1]=WKb; cp.d[2]=WVb; cp.d[3]=WGb; cp.d[4]=WOb;
  cast5_k<<<dim3(1024, 5), 256, 0, stream>>>(cp);
  PrepP pp;
  pp.mw1 = MW1; pp.mw2 = MW2; pp.tdw1 = TDW1; pp.tdw2 = TDW2;
  pp.w1t = W1T; pp.w2t = W2T; pp.tw1t = TW1T; pp.tw2t = TW2T;
  prep_k<<<dim3(1024, 4), 256, 0, stream>>>(pp);

  // XM / XBF / XX
  mkxm_k<<<8192, 256, 0, stream>>>(X, TMX, XM, XBF, XX);

  // mix160 = tanh(XM @ maa_w1)        [8192,256(pad)]
  gemm_bt<1><<<dim3(64, 2), 256, 0, stream>>>(XM, 1024, W1T, 1024, MIXB, 256, 1024, nullptr);

  // x{w,k,v,r,g} = x + xx*(tm + mix_f @ maa_w2_f)   — one launch, z-loop inside
  Mix5P mp;
  mp.ex = XBF; mp.exx = XX;
  mp.out[0]=XW; mp.out[1]=XK; mp.out[2]=XV; mp.out[3]=XR; mp.out[4]=XG;
  mp.tm[0]=TMW; mp.tm[1]=TMK; mp.tm[2]=TMV; mp.tm[3]=TMR; mp.tm[4]=TMG;
  gemm_mix5<<<dim3(64, 8), 256, 0, stream>>>(MIXB, W2T, mp);

  // r, k, v, g — fused 128^2-block 4-wave TLP kernel (4 blocks/CU)
  G4P gp;
  gp.A[0]=XR; gp.A[1]=XK; gp.A[2]=XV; gp.A[3]=XG;
  gp.B[0]=WRb; gp.B[1]=WKb; gp.B[2]=WVb; gp.B[3]=WGb;
  gp.C[0]=Rb; gp.C[1]=Kb; gp.C[2]=Vb; gp.C[3]=Gb;
  gemm128_k<0><<<dim3(64, 8, 4), 256, 0, stream>>>(gp, nullptr);

  // h = tanh(xw @ td_w1);  decay = exp(-exp(time_decay + h @ td_w2))
  gemm_bt<1><<<dim3(64, 1), 256, 0, stream>>>(XW, 1024, TW1T, 1024, Hb, 128, 1024, nullptr);
  gemm_bt<3><<<dim3(64, 8), 256, 0, stream>>>(Hb, 128, TW2T, 64, DEC, 1024, 64, TD);

  // WKV6 chunk-parallel scan (Y bf16)
  wkv_s1<<<2048, 256, 0, stream>>>(Rb, Kb, Vb, DEC, U, Y, Ab, Pg);
  wkv_s2<<<256, 256, 0, stream>>>(Ab, Pg, Sg);
  wkv_s3<<<2048, 256, 0, stream>>>(Rb, Sg, Y);

  // GroupNorm(y)*g -> z
  gnorm_k<<<8192, 256, 0, stream>>>(Y, Gb, LNG, LNB, Z);

  // out = z @ Wo^T   (f32 out)
  G4P go;
  go.A[0]=Z; go.B[0]=WOb; go.C[0]=nullptr;
  gemm128_k<1><<<dim3(64, 8, 1), 256, 0, stream>>>(go, (float*)d_out);
}